// Round 16
// baseline (301.528 us; speedup 1.0000x reference)
//
#include <hip/hip_runtime.h>
#include <stdint.h>

// ---------------------------------------------------------------------------
// MHA: B=4 S=2048 H=16 Dk=Dv=64 HIDDEN=1024, fp32 in/out, bf16 MFMA compute.
// Pipeline: detect -> pack_w -> cvt_x(all 3) -> gemm_qkv(MERGED z, BK=32,
//           z=2 writes V TRANSPOSED in-epilogue) -> mask_bits -> attn -> gemm_out
// Round 16: transpose_v kernel ELIMINATED. The std V layout was read only by
// transpose_v, so z=2 GEMM blocks now write VT[bh][dv][s] directly into their
// own QKV z=2 slice via a wave-private 64x64 LDS transpose (reuses lA/lB after
// the mainloop's final barrier; swizzle formulas identical to the validated
// transpose_v kernel). Saves 32MB of traffic + one launch (~6-8us).
// Scratch ws (72 MiB + 4B):
//   [0,16MiB)   Xq (bf16) ... later reused as Ob (attn out)
//   [16,24MiB)  Wt  (packed bf16 weights, 4x 1024x1024, N-major)
//   [24,72MiB)  QKV (bf16): z=0 Q, z=1 K (std [bh][s][64]); z=2 VT [bh][dv][s]
//   @72MiB      mask-dtype flag (4B)
// d_out overlay (32 MiB): qkv phase: Xk [0,16), Xv [16,32);
//   after: bitmask [16,18). gemm_out overwrites all at the end.
// ---------------------------------------------------------------------------

typedef __bf16 bf16x8_t __attribute__((ext_vector_type(8)));
typedef float f32x4_t __attribute__((ext_vector_type(4)));
typedef short s16x4_t __attribute__((ext_vector_type(4)));

#define HID   1024
#define SLEN  2048
#define BATCH 4
#define NH    16
#define MROWS 8192   // BATCH*SLEN
#define L2E   1.44269504f

__device__ __forceinline__ unsigned short bfbits(float f) {
  union { __bf16 h; unsigned short u; } v; v.h = (__bf16)f; return v.u;
}
__device__ __forceinline__ unsigned int packbf(float a, float b) {
  return (unsigned int)bfbits(a) | ((unsigned int)bfbits(b) << 16);
}
__device__ __forceinline__ float fast_exp2(float x) {
#if __has_builtin(__builtin_amdgcn_exp2f)
  return __builtin_amdgcn_exp2f(x);
#else
  return __exp2f(x);
#endif
}

__device__ __forceinline__ f32x4_t mfma16x16(s16x4_t a, s16x4_t b, f32x4_t c) {
#if __has_builtin(__builtin_amdgcn_mfma_f32_16x16x16bf16_1k)
  return __builtin_amdgcn_mfma_f32_16x16x16bf16_1k(a, b, c, 0, 0, 0);
#else
  asm("v_mfma_f32_16x16x16_bf16 %0, %1, %2, %0" : "+v"(c) : "v"(a), "v"(b));
  return c;
#endif
}

__device__ __forceinline__ void gload_lds16(const void* g, void* l) {
  __builtin_amdgcn_global_load_lds((const __attribute__((address_space(1))) void*)g,
                                   (__attribute__((address_space(3))) void*)l,
                                   16, 0, 0);
}

// 64-wide LDS rows (128B, 8 slots of 16B): physical slot = logical ^ (row & 7)
__device__ __forceinline__ bf16x8_t frag_ld(const unsigned short* lds, int row, int sblk) {
  int sp = sblk ^ (row & 7);
  return *(const bf16x8_t*)(lds + (row << 6) + (sp << 3));
}
// 32-wide LDS rows (64B, 4 slots of 16B): slot = logical ^ (row&3) ^ ((row>>2)&3)
__device__ __forceinline__ bf16x8_t frag_ld32(const unsigned short* lds, int row, int g) {
  int sp = g ^ (row & 3) ^ ((row >> 2) & 3);
  return *(const bf16x8_t*)(lds + (row << 5) + (sp << 3));
}

// ---- mask dtype detector: bool bytes (1B) vs int32 --------------------------
__global__ void detect_mask_kernel(const unsigned int* __restrict__ m,
                                   unsigned int* __restrict__ flag) {
  unsigned int v = m[threadIdx.x];
  unsigned long long b = __ballot(v > 1u);         // packed bools give words > 1
  if (threadIdx.x == 0) flag[0] = 0u;
  __syncthreads();
  if ((threadIdx.x & 63) == 0 && b) atomicOr(flag, 1u);  // 1 => byte mask
}

// ---- mask -> bitmask: bits[(b*S+q)*32 + kw] bit i = mask[b][q][kw*64+i] -----
__global__ __launch_bounds__(256) void mask_bits_kernel(const void* __restrict__ maskp,
    const unsigned int* __restrict__ flag, unsigned long long* __restrict__ bits) {
  int lane = threadIdx.x & 63, wv = threadIdx.x >> 6;
  bool bytemask = flag[0] != 0u;
  size_t w0 = (size_t)blockIdx.x * 64 + (size_t)wv * 16;
  for (int it = 0; it < 16; ++it) {
    size_t word = w0 + it;
    unsigned int v;
    if (bytemask) v = ((const unsigned char*)maskp)[word * 64 + lane];
    else          v = ((const unsigned int*)maskp)[word * 64 + lane];
    unsigned long long bm = __ballot(v != 0u);
    if (lane == 0) bits[word] = bm;
  }
}

// ---- fp32 -> bf16 conversion of all three hidden inputs ---------------------
__global__ __launch_bounds__(256) void cvt_x_kernel(const float* __restrict__ xq,
    const float* __restrict__ xk, const float* __restrict__ xv,
    unsigned short* __restrict__ dq, unsigned short* __restrict__ dk,
    unsigned short* __restrict__ dv) {
  int z = blockIdx.y;
  const float* src = z == 0 ? xq : (z == 1 ? xk : xv);
  unsigned short* dst = z == 0 ? dq : (z == 1 ? dk : dv);
  size_t base = (size_t)blockIdx.x * 1024 + (size_t)threadIdx.x * 4;
  float4 v = *(const float4*)(src + base);
  ushort4 o;
  o.x = bfbits(v.x); o.y = bfbits(v.y); o.z = bfbits(v.z); o.w = bfbits(v.w);
  *(ushort4*)(dst + base) = o;
}

// ---- pack weights into bf16, N-major: Wt[z][n][k] ---------------------------
__global__ __launch_bounds__(256) void pack_w_kernel(const float* __restrict__ wq,
    const float* __restrict__ wk, const float* __restrict__ wv,
    const float* __restrict__ wo, unsigned short* __restrict__ wt) {
  int z = blockIdx.y;
  int id = blockIdx.x * 256 + threadIdx.x;
  int n = id >> 8;
  int d0 = (id & 255) << 2;
  ushort4 o;
  if (z < 3) {
    const float* w = z == 0 ? wq : (z == 1 ? wk : wv);
    const float* base = w + (size_t)(n >> 6) * (HID * 64) + (n & 63);
    o.x = bfbits(base[(size_t)(d0 + 0) * 64]);
    o.y = bfbits(base[(size_t)(d0 + 1) * 64]);
    o.z = bfbits(base[(size_t)(d0 + 2) * 64]);
    o.w = bfbits(base[(size_t)(d0 + 3) * 64]);
  } else {
    o.x = bfbits(wo[(size_t)(d0 + 0) * HID + n]);
    o.y = bfbits(wo[(size_t)(d0 + 1) * HID + n]);
    o.z = bfbits(wo[(size_t)(d0 + 2) * HID + n]);
    o.w = bfbits(wo[(size_t)(d0 + 3) * HID + n]);
  }
  *(ushort4*)(wt + (size_t)z * (HID * HID) + (size_t)n * HID + d0) = o;
}

// ---- MERGED QKV GEMM: 128x128 tile, BK=32, dbuf LDS 32KB --------------------
// z=0: Q std layout (scaled); z=1: K std; z=2: V written TRANSPOSED [bh][dv][s]
__device__ __forceinline__ void gemm_stage32(const unsigned short* __restrict__ A,
    const unsigned short* __restrict__ B, unsigned short* la, unsigned short* lb,
    int tid, int w, int kt) {
#pragma unroll
  for (int i = 0; i < 2; ++i) {
    int flat = i * 256 + tid;
    int row = flat >> 2;
    int sl = (flat & 3) ^ (row & 3) ^ ((row >> 2) & 3);  // inverse-swz SOURCE
    gload_lds16(A + (size_t)row * HID + kt + sl * 8, la + ((i * 256 + w * 64) << 3));
    gload_lds16(B + (size_t)row * HID + kt + sl * 8, lb + ((i * 256 + w * 64) << 3));
  }
}

__global__ __launch_bounds__(256) void gemm_qkv_kernel(
    const unsigned short* __restrict__ Xq, const unsigned short* __restrict__ Xk,
    const unsigned short* __restrict__ Xv, const unsigned short* __restrict__ Wt,
    const float* __restrict__ bq, const float* __restrict__ bk,
    const float* __restrict__ bv, unsigned short* __restrict__ QKV) {
  __shared__ __align__(16) unsigned short lA[2][128 * 32];
  __shared__ __align__(16) unsigned short lB[2][128 * 32];
  int z = blockIdx.z;
  const unsigned short* Ain = z == 0 ? Xq : (z == 1 ? Xk : Xv);
  const float* bias = z == 0 ? bq : (z == 1 ? bk : bv);
  float scale = z == 0 ? 0.125f * L2E : 1.0f;
  int m0 = blockIdx.x * 128, n0 = blockIdx.y * 128;
  const unsigned short* A = Ain + (size_t)m0 * HID;
  const unsigned short* B = Wt + (size_t)z * (HID * HID) + (size_t)n0 * HID;
  unsigned short* Out = QKV + (size_t)z * ((size_t)MROWS * 1024);

  f32x4_t acc[4][4] = {};
  int tid = threadIdx.x, lane = tid & 63, w = tid >> 6;
  int wr = (w >> 1) << 6, wc = (w & 1) << 6;
  int ql = lane & 15, g = lane >> 4;

  gemm_stage32(A, B, lA[0], lB[0], tid, w, 0);
  __syncthreads();
  int cur = 0;
  for (int kt = 0; kt < HID; kt += 32) {
    if (kt + 32 < HID)
      gemm_stage32(A, B, lA[cur ^ 1], lB[cur ^ 1], tid, w, kt + 32);
    const unsigned short* la = lA[cur];
    const unsigned short* lb = lB[cur];
    bf16x8_t af[4], bfr[4];
#pragma unroll
    for (int mi = 0; mi < 4; ++mi)
      af[mi] = frag_ld32(la, wr + mi * 16 + ql, g);
#pragma unroll
    for (int ni = 0; ni < 4; ++ni)
      bfr[ni] = frag_ld32(lb, wc + ni * 16 + ql, g);
#pragma unroll
    for (int mi = 0; mi < 4; ++mi)
#pragma unroll
      for (int ni = 0; ni < 4; ++ni)
        acc[mi][ni] = __builtin_amdgcn_mfma_f32_16x16x32_bf16(af[mi], bfr[ni],
                                                              acc[mi][ni], 0, 0, 0);
    __syncthreads();
    cur ^= 1;
  }

  if (z < 2) {
    // standard [b][h][s][64] store (Q scaled, K unscaled)
#pragma unroll
    for (int mi = 0; mi < 4; ++mi)
#pragma unroll
      for (int ni = 0; ni < 4; ++ni) {
        int col = n0 + wc + ni * 16 + ql;
        float bb = bias[col];
        int h = col >> 6, d = col & 63;
#pragma unroll
        for (int r = 0; r < 4; ++r) {
          int row = m0 + wr + mi * 16 + (g << 2) + r;
          int b = row >> 11, s = row & 2047;
          Out[((((size_t)b * NH + h) * SLEN + s) << 6) + d] =
              bfbits((acc[mi][ni][r] + bb) * scale);
        }
      }
  } else {
    // V: transpose in wave-private 8KB LDS (post-barrier reuse of lA/lB),
    // then coalesced store as VT[bh][dv][s]. Formulas = transpose_v kernel.
    unsigned short* tb = (w < 2) ? lA[w] : lB[w - 2];  // [64 d][32 u32] region
    unsigned int* tu = (unsigned int*)tb;
#pragma unroll
    for (int mi = 0; mi < 4; ++mi)
#pragma unroll
      for (int ni = 0; ni < 4; ++ni) {
        int col = n0 + wc + ni * 16 + ql;
        float bb = bias[col];
        int dl = ni * 16 + ql;                 // d_local 0..63
        int sp0 = 8 * mi + 2 * g;              // s-pair index (even)
        unsigned int v0 = packbf(acc[mi][ni][0] + bb, acc[mi][ni][1] + bb);
        unsigned int v1 = packbf(acc[mi][ni][2] + bb, acc[mi][ni][3] + bb);
        int slot = (sp0 >> 2) ^ (dl & 7);      // sp0,sp0+1 share this slot
        *(uint2*)(tu + dl * 32 + slot * 4 + (sp0 & 3)) = make_uint2(v0, v1);
      }
    // wave-private: compiler's lgkm waits order write->read; no barrier needed
    int srow = m0 + wr;                        // 64-aligned: single batch
    int b = srow >> 11, sl_ = srow & 2047;
    int h = (n0 + wc) >> 6;                    // 64-aligned cols: single head
    unsigned short* VTo = Out + (((size_t)(b * NH + h) * 64) * SLEN);
#pragma unroll
    for (int pass = 0; pass < 8; ++pass) {
      int dl = (lane >> 3) + 8 * pass;
      int slot = lane & 7;
      uint4 vv = *(const uint4*)(tu + dl * 32 + ((slot ^ (dl & 7)) << 2));
      *(uint4*)(VTo + (size_t)dl * SLEN + sl_ + slot * 8) = vv;
    }
  }
}

// ---- output projection GEMM: champion BK=64 2-phase -------------------------
__device__ __forceinline__ void gemm_stage(const unsigned short* __restrict__ A,
    const unsigned short* __restrict__ B, unsigned short* la, unsigned short* lb,
    int tid, int w, int kt) {
#pragma unroll
  for (int i = 0; i < 4; ++i) {
    int flat = i * 256 + tid;
    int row = flat >> 3;
    int sl = (flat & 7) ^ (row & 7);
    gload_lds16(A + (size_t)row * HID + kt + sl * 8, la + ((i * 256 + w * 64) << 3));
    gload_lds16(B + (size_t)row * HID + kt + sl * 8, lb + ((i * 256 + w * 64) << 3));
  }
}

__global__ __launch_bounds__(256) void gemm_out_kernel(
    const unsigned short* __restrict__ Ob, const unsigned short* __restrict__ WoT,
    const float* __restrict__ bo, float* __restrict__ out) {
  __shared__ __align__(16) unsigned short lA[2][128 * 64];
  __shared__ __align__(16) unsigned short lB[2][128 * 64];
  int m0 = blockIdx.x * 128, n0 = blockIdx.y * 128;
  const unsigned short* A = Ob + (size_t)m0 * HID;
  const unsigned short* B = WoT + (size_t)n0 * HID;
  f32x4_t acc[4][4] = {};
  int tid = threadIdx.x;
  int lane = tid & 63, w = tid >> 6;
  int wr = (w >> 1) << 6, wc = (w & 1) << 6;
  gemm_stage(A, B, lA[0], lB[0], tid, w, 0);
  __syncthreads();
  int cur = 0;
  for (int kt = 0; kt < HID; kt += 64) {
    if (kt + 64 < HID)
      gemm_stage(A, B, lA[cur ^ 1], lB[cur ^ 1], tid, w, kt + 64);
    const unsigned short* la = lA[cur];
    const unsigned short* lb = lB[cur];
#pragma unroll
    for (int kk = 0; kk < 2; ++kk) {
      bf16x8_t af[4], bfr[4];
#pragma unroll
      for (int mi = 0; mi < 4; ++mi)
        af[mi] = frag_ld(la, wr + mi * 16 + (lane & 15), kk * 4 + (lane >> 4));
#pragma unroll
      for (int ni = 0; ni < 4; ++ni)
        bfr[ni] = frag_ld(lb, wc + ni * 16 + (lane & 15), kk * 4 + (lane >> 4));
#pragma unroll
      for (int mi = 0; mi < 4; ++mi)
#pragma unroll
        for (int ni = 0; ni < 4; ++ni)
          acc[mi][ni] = __builtin_amdgcn_mfma_f32_16x16x32_bf16(af[mi], bfr[ni],
                                                                acc[mi][ni], 0, 0, 0);
    }
    __syncthreads();
    cur ^= 1;
  }
#pragma unroll
  for (int mi = 0; mi < 4; ++mi)
#pragma unroll
    for (int ni = 0; ni < 4; ++ni) {
      int col = n0 + wc + ni * 16 + (lane & 15);
      float bb = bo[col];
#pragma unroll
      for (int r = 0; r < 4; ++r) {
        int row = m0 + wr + mi * 16 + ((lane >> 4) << 2) + r;
        out[(size_t)row * HID + col] = acc[mi][ni][r] + bb;
      }
    }
}

// ---- flash attention: champion (swapped QK^T, static-max, register-P PV) ----
__global__ __launch_bounds__(256) void attn_kernel(
    const unsigned short* __restrict__ Q, const unsigned short* __restrict__ K,
    const unsigned short* __restrict__ VT, const unsigned long long* __restrict__ mbits,
    unsigned short* __restrict__ O) {
  __shared__ __align__(16) unsigned short lK[2][64 * 64];  // [kv][d]  swizzled
  __shared__ __align__(16) unsigned short lV[2][64 * 64];  // [dv][kv] swizzled
  int tid = threadIdx.x, lane = tid & 63, w = tid >> 6;
  int g = lane >> 4, ql = lane & 15;
  int bid = blockIdx.x;
  int bh = (bid & 7) * 8 + ((bid >> 3) >> 4);
  int qt = (bid >> 3) & 15;
  int b = bh >> 4, h = bh & 15;
  int q0 = qt * 128;
  const unsigned short* Qb = Q + (size_t)bh * (SLEN * 64);

  int f0 = tid, f1 = 256 + tid;
  int r0 = f0 >> 3, r1 = f1 >> 3;
  int s0 = (f0 & 7) ^ (r0 & 7), s1 = (f1 & 7) ^ (r1 & 7);
  const unsigned short* kS0 = K + (size_t)bh * (SLEN * 64) + (size_t)r0 * 64 + s0 * 8;
  const unsigned short* kS1 = K + (size_t)bh * (SLEN * 64) + (size_t)r1 * 64 + s1 * 8;
  const unsigned short* vS0 = VT + (size_t)bh * (64 * SLEN) + (size_t)r0 * SLEN + s0 * 8;
  const unsigned short* vS1 = VT + (size_t)bh * (64 * SLEN) + (size_t)r1 * SLEN + s1 * 8;
  int d0off = (0 * 256 + w * 64) << 3;
  int d1off = (1 * 256 + w * 64) << 3;
  const unsigned long long* mp0 = mbits + ((size_t)b * SLEN + (q0 + w * 32 + ql)) * 32;
  const unsigned long long* mp1 = mp0 + 16 * 32;

  int vbyte0 = (ql << 7) + (((g >> 1) ^ (ql & 7)) << 4) + ((g & 1) << 3);

  bf16x8_t qf[2][2];
#pragma unroll
  for (int mi = 0; mi < 2; ++mi)
#pragma unroll
    for (int kk = 0; kk < 2; ++kk) {
      int row = q0 + w * 32 + mi * 16 + ql;
      qf[mi][kk] = *(const bf16x8_t*)(Qb + (size_t)row * 64 + kk * 32 + g * 8);
    }

  s16x4_t ones4 = {0x3F80, 0x3F80, 0x3F80, 0x3F80};  // 4x bf16 1.0

  f32x4_t aco[2][4] = {};     // O^T: dv=dvf*16+4g+r, q=mi*16+ql
  f32x4_t slacc[2] = {};      // l[q=ql] via ones-MFMA

  gload_lds16(kS0, (unsigned short*)lK[0] + d0off);
  gload_lds16(kS1, (unsigned short*)lK[0] + d1off);
  gload_lds16(vS0, (unsigned short*)lV[0] + d0off);
  gload_lds16(vS1, (unsigned short*)lV[0] + d1off);
  kS0 += 4096; kS1 += 4096; vS0 += 64; vS1 += 64;
  __syncthreads();

  int cur = 0;
  for (int kt = 0; kt < SLEN / 64; ++kt) {
    if (kt + 1 < SLEN / 64) {
      unsigned short* kn = (unsigned short*)lK[cur ^ 1];
      unsigned short* vn = (unsigned short*)lV[cur ^ 1];
      gload_lds16(kS0, kn + d0off);
      gload_lds16(kS1, kn + d1off);
      gload_lds16(vS0, vn + d0off);
      gload_lds16(vS1, vn + d1off);
      kS0 += 4096; kS1 += 4096; vS0 += 64; vS1 += 64;
    }

    unsigned long long bg0 = mp0[kt] >> (4 * g);
    unsigned long long bg1 = mp1[kt] >> (4 * g);

    const unsigned short* kbuf = lK[cur];
    const unsigned short* vbuf = lV[cur];
    f32x4_t st[2][4];
#pragma unroll
    for (int mi = 0; mi < 2; ++mi)
#pragma unroll
      for (int ni = 0; ni < 4; ++ni) st[mi][ni] = (f32x4_t){0.f, 0.f, 0.f, 0.f};
    __builtin_amdgcn_s_setprio(1);
#pragma unroll
    for (int kk = 0; kk < 2; ++kk) {
      bf16x8_t kf[4];
#pragma unroll
      for (int ni = 0; ni < 4; ++ni)
        kf[ni] = frag_ld(kbuf, ni * 16 + ql, kk * 4 + g);
#pragma unroll
      for (int mi = 0; mi < 2; ++mi)
#pragma unroll
        for (int ni = 0; ni < 4; ++ni)
          st[mi][ni] = __builtin_amdgcn_mfma_f32_16x16x32_bf16(kf[ni], qf[mi][kk],
                                                               st[mi][ni], 0, 0, 0);
    }
    __builtin_amdgcn_s_setprio(0);

    unsigned int pb[2][4][2];
#pragma unroll
    for (int mi = 0; mi < 2; ++mi) {
      unsigned long long bgs = mi ? bg1 : bg0;
      unsigned int mw0 = (unsigned int)bgs;
      unsigned int mw1 = (unsigned int)(bgs >> 32);
#pragma unroll
      for (int ni = 0; ni < 4; ++ni) {
        unsigned int mword = (ni < 2) ? mw0 : mw1;
        int base = (ni & 1) * 16;
        float p[4];
#pragma unroll
        for (int r = 0; r < 4; ++r) {
          float e = fast_exp2(st[mi][ni][r]);
          p[r] = ((mword >> (base + r)) & 1u) ? e : 0.f;
        }
        pb[mi][ni][0] = packbf(p[0], p[1]);
        pb[mi][ni][1] = packbf(p[2], p[3]);
      }
    }

    __builtin_amdgcn_s_setprio(1);
#pragma unroll
    for (int c = 0; c < 4; ++c) {
      s16x4_t vfa[4];
#pragma unroll
      for (int dvf = 0; dvf < 4; ++dvf) {
        union { uint2 u; s16x4_t s; } t;
        t.u = *(const uint2*)((const char*)vbuf + ((vbyte0 ^ (c << 5)) + dvf * 2048));
        vfa[dvf] = t.s;
      }
#pragma unroll
      for (int mi = 0; mi < 2; ++mi) {
        union { unsigned int u[2]; s16x4_t s; } pp;
        pp.u[0] = pb[mi][c][0]; pp.u[1] = pb[mi][c][1];
        slacc[mi] = mfma16x16(ones4, pp.s, slacc[mi]);
#pragma unroll
        for (int dvf = 0; dvf < 4; ++dvf)
          aco[mi][dvf] = mfma16x16(vfa[dvf], pp.s, aco[mi][dvf]);
      }
    }
    __builtin_amdgcn_s_setprio(0);

    __syncthreads();
    cur ^= 1;
  }

  unsigned short* eb = (unsigned short*)lK;  // 16KB scratch, rows [128][128B]
#pragma unroll
  for (int mi = 0; mi < 2; ++mi) {
    float inv = 1.0f / slacc[mi][0];
    int prow = w * 32 + mi * 16 + ql;
#pragma unroll
    for (int dvf = 0; dvf < 4; ++dvf) {
      unsigned int lo = packbf(aco[mi][dvf][0] * inv, aco[mi][dvf][1] * inv);
      unsigned int hi = packbf(aco[mi][dvf][2] * inv, aco[mi][dvf][3] * inv);
      int sl = (2 * dvf + (g >> 1)) ^ (prow & 7);
      *(uint2*)((char*)eb + prow * 128 + sl * 16 + (g & 1) * 8) = make_uint2(lo, hi);
    }
  }
#pragma unroll
  for (int it = 0; it < 8; ++it) {
    int rloc = g + 4 * it;
    int row = w * 32 + rloc;
    int sl = (ql >> 1) ^ (row & 7);
    uint2 v = *(const uint2*)((const char*)eb + row * 128 + sl * 16 + (ql & 1) * 8);
    int qrow = q0 + row;
    *(uint2*)(O + (((size_t)b * SLEN + qrow) << 10) + h * 64 + ql * 4) = v;
  }
}

// ---------------------------------------------------------------------------
extern "C" void kernel_launch(void* const* d_in, const int* in_sizes, int n_in,
                              void* d_out, int out_size, void* d_ws, size_t ws_size,
                              hipStream_t stream) {
  (void)in_sizes; (void)n_in; (void)out_size; (void)ws_size;
  const float* xq = (const float*)d_in[0];
  const float* xk = (const float*)d_in[1];
  const float* xv = (const float*)d_in[2];
  const void*  mask = d_in[3];
  const float* wq = (const float*)d_in[4];
  const float* bq = (const float*)d_in[5];
  const float* wk = (const float*)d_in[6];
  const float* bk = (const float*)d_in[7];
  const float* wv = (const float*)d_in[8];
  const float* bv = (const float*)d_in[9];
  const float* wo = (const float*)d_in[10];
  const float* bo = (const float*)d_in[11];
  float* out = (float*)d_out;

  char* ws = (char*)d_ws;
  unsigned short* Xq   = (unsigned short*)(ws);                   // 16 MiB, later Ob
  unsigned short* Ob   = (unsigned short*)(ws);                   // overlays Xq
  unsigned short* Wt   = (unsigned short*)(ws + 16777216ull);     // 8 MiB packed weights
  unsigned short* QKV  = (unsigned short*)(ws + 25165824ull);     // 48 MiB
  unsigned int*   flag = (unsigned int*)(ws + 75497472ull);       // 4 B
  // d_out overlay (32 MiB): qkv phase Xk [0,16M), Xv [16,32M);
  // afterwards bitmask [16M,18M). gemm_out overwrites at the end.
  unsigned short* Xk  = (unsigned short*)d_out;
  unsigned short* Xv  = (unsigned short*)((char*)d_out + 16777216ull);
  unsigned long long* mbits = (unsigned long long*)((char*)d_out + 16777216ull);

  detect_mask_kernel<<<1, 256, 0, stream>>>((const unsigned int*)mask, flag);
  pack_w_kernel<<<dim3(1024, 4), 256, 0, stream>>>(wq, wk, wv, wo, Wt);
  cvt_x_kernel<<<dim3(8192, 3), 256, 0, stream>>>(xq, xk, xv, Xq, Xk, Xv);
  gemm_qkv_kernel<<<dim3(64, 8, 3), 256, 0, stream>>>(Xq, Xk, Xv, Wt, bq, bk, bv, QKV);
  mask_bits_kernel<<<4096, 256, 0, stream>>>(mask, flag, mbits);   // Xv region now dead
  attn_kernel<<<1024, 256, 0, stream>>>(QKV, QKV + 8388608ull,
                                        QKV + 16777216ull, mbits, Ob);  // Xq dead
  gemm_out_kernel<<<dim3(64, 8), 256, 0, stream>>>(Ob, Wt + 3ull * (HID * HID), bo, out);
}

// Round 17
// 291.850 us; speedup vs baseline: 1.0332x; 1.0332x over previous
//
#include <hip/hip_runtime.h>
#include <stdint.h>

// ---------------------------------------------------------------------------
// MHA: B=4 S=2048 H=16 Dk=Dv=64 HIDDEN=1024, fp32 in/out, bf16 MFMA compute.
// Pipeline: detect -> pack_w -> cvt_x(all 3) -> gemm_qkv(MERGED z, BK=32,
//           z=2 writes V TRANSPOSED in-epilogue) -> mask_bits -> attn -> gemm_out
// Round 17: attn KVBLK 64 -> 128 (parameter change). Per barrier, TWO 64-kv
// halves are processed (champion per-half body verbatim, h=0,1); barrier
// count per block halves 32 -> 16+1. Attacks the measured ~1500cy/tile of
// exposed latency (MFMA ~1000 + VALU ~640 vs 2570 total). LDS 32->64KB.
// Scratch ws (72 MiB + 4B):
//   [0,16MiB)   Xq (bf16) ... later reused as Ob (attn out)
//   [16,24MiB)  Wt  (packed bf16 weights, 4x 1024x1024, N-major)
//   [24,72MiB)  QKV (bf16): z=0 Q, z=1 K (std [bh][s][64]); z=2 VT [bh][dv][s]
//   @72MiB      mask-dtype flag (4B)
// d_out overlay (32 MiB): qkv phase: Xk [0,16), Xv [16,32);
//   after: bitmask [16,18). gemm_out overwrites all at the end.
// ---------------------------------------------------------------------------

typedef __bf16 bf16x8_t __attribute__((ext_vector_type(8)));
typedef float f32x4_t __attribute__((ext_vector_type(4)));
typedef short s16x4_t __attribute__((ext_vector_type(4)));

#define HID   1024
#define SLEN  2048
#define BATCH 4
#define NH    16
#define MROWS 8192   // BATCH*SLEN
#define L2E   1.44269504f

__device__ __forceinline__ unsigned short bfbits(float f) {
  union { __bf16 h; unsigned short u; } v; v.h = (__bf16)f; return v.u;
}
__device__ __forceinline__ unsigned int packbf(float a, float b) {
  return (unsigned int)bfbits(a) | ((unsigned int)bfbits(b) << 16);
}
__device__ __forceinline__ float fast_exp2(float x) {
#if __has_builtin(__builtin_amdgcn_exp2f)
  return __builtin_amdgcn_exp2f(x);
#else
  return __exp2f(x);
#endif
}

__device__ __forceinline__ f32x4_t mfma16x16(s16x4_t a, s16x4_t b, f32x4_t c) {
#if __has_builtin(__builtin_amdgcn_mfma_f32_16x16x16bf16_1k)
  return __builtin_amdgcn_mfma_f32_16x16x16bf16_1k(a, b, c, 0, 0, 0);
#else
  asm("v_mfma_f32_16x16x16_bf16 %0, %1, %2, %0" : "+v"(c) : "v"(a), "v"(b));
  return c;
#endif
}

__device__ __forceinline__ void gload_lds16(const void* g, void* l) {
  __builtin_amdgcn_global_load_lds((const __attribute__((address_space(1))) void*)g,
                                   (__attribute__((address_space(3))) void*)l,
                                   16, 0, 0);
}

// 64-wide LDS rows (128B, 8 slots of 16B): physical slot = logical ^ (row & 7)
__device__ __forceinline__ bf16x8_t frag_ld(const unsigned short* lds, int row, int sblk) {
  int sp = sblk ^ (row & 7);
  return *(const bf16x8_t*)(lds + (row << 6) + (sp << 3));
}
// 32-wide LDS rows (64B, 4 slots of 16B): slot = logical ^ (row&3) ^ ((row>>2)&3)
__device__ __forceinline__ bf16x8_t frag_ld32(const unsigned short* lds, int row, int g) {
  int sp = g ^ (row & 3) ^ ((row >> 2) & 3);
  return *(const bf16x8_t*)(lds + (row << 5) + (sp << 3));
}

// ---- mask dtype detector: bool bytes (1B) vs int32 --------------------------
__global__ void detect_mask_kernel(const unsigned int* __restrict__ m,
                                   unsigned int* __restrict__ flag) {
  unsigned int v = m[threadIdx.x];
  unsigned long long b = __ballot(v > 1u);         // packed bools give words > 1
  if (threadIdx.x == 0) flag[0] = 0u;
  __syncthreads();
  if ((threadIdx.x & 63) == 0 && b) atomicOr(flag, 1u);  // 1 => byte mask
}

// ---- mask -> bitmask: bits[(b*S+q)*32 + kw] bit i = mask[b][q][kw*64+i] -----
__global__ __launch_bounds__(256) void mask_bits_kernel(const void* __restrict__ maskp,
    const unsigned int* __restrict__ flag, unsigned long long* __restrict__ bits) {
  int lane = threadIdx.x & 63, wv = threadIdx.x >> 6;
  bool bytemask = flag[0] != 0u;
  size_t w0 = (size_t)blockIdx.x * 64 + (size_t)wv * 16;
  for (int it = 0; it < 16; ++it) {
    size_t word = w0 + it;
    unsigned int v;
    if (bytemask) v = ((const unsigned char*)maskp)[word * 64 + lane];
    else          v = ((const unsigned int*)maskp)[word * 64 + lane];
    unsigned long long bm = __ballot(v != 0u);
    if (lane == 0) bits[word] = bm;
  }
}

// ---- fp32 -> bf16 conversion of all three hidden inputs ---------------------
__global__ __launch_bounds__(256) void cvt_x_kernel(const float* __restrict__ xq,
    const float* __restrict__ xk, const float* __restrict__ xv,
    unsigned short* __restrict__ dq, unsigned short* __restrict__ dk,
    unsigned short* __restrict__ dv) {
  int z = blockIdx.y;
  const float* src = z == 0 ? xq : (z == 1 ? xk : xv);
  unsigned short* dst = z == 0 ? dq : (z == 1 ? dk : dv);
  size_t base = (size_t)blockIdx.x * 1024 + (size_t)threadIdx.x * 4;
  float4 v = *(const float4*)(src + base);
  ushort4 o;
  o.x = bfbits(v.x); o.y = bfbits(v.y); o.z = bfbits(v.z); o.w = bfbits(v.w);
  *(ushort4*)(dst + base) = o;
}

// ---- pack weights into bf16, N-major: Wt[z][n][k] ---------------------------
__global__ __launch_bounds__(256) void pack_w_kernel(const float* __restrict__ wq,
    const float* __restrict__ wk, const float* __restrict__ wv,
    const float* __restrict__ wo, unsigned short* __restrict__ wt) {
  int z = blockIdx.y;
  int id = blockIdx.x * 256 + threadIdx.x;
  int n = id >> 8;
  int d0 = (id & 255) << 2;
  ushort4 o;
  if (z < 3) {
    const float* w = z == 0 ? wq : (z == 1 ? wk : wv);
    const float* base = w + (size_t)(n >> 6) * (HID * 64) + (n & 63);
    o.x = bfbits(base[(size_t)(d0 + 0) * 64]);
    o.y = bfbits(base[(size_t)(d0 + 1) * 64]);
    o.z = bfbits(base[(size_t)(d0 + 2) * 64]);
    o.w = bfbits(base[(size_t)(d0 + 3) * 64]);
  } else {
    o.x = bfbits(wo[(size_t)(d0 + 0) * HID + n]);
    o.y = bfbits(wo[(size_t)(d0 + 1) * HID + n]);
    o.z = bfbits(wo[(size_t)(d0 + 2) * HID + n]);
    o.w = bfbits(wo[(size_t)(d0 + 3) * HID + n]);
  }
  *(ushort4*)(wt + (size_t)z * (HID * HID) + (size_t)n * HID + d0) = o;
}

// ---- MERGED QKV GEMM: 128x128 tile, BK=32, dbuf LDS 32KB --------------------
__device__ __forceinline__ void gemm_stage32(const unsigned short* __restrict__ A,
    const unsigned short* __restrict__ B, unsigned short* la, unsigned short* lb,
    int tid, int w, int kt) {
#pragma unroll
  for (int i = 0; i < 2; ++i) {
    int flat = i * 256 + tid;
    int row = flat >> 2;
    int sl = (flat & 3) ^ (row & 3) ^ ((row >> 2) & 3);  // inverse-swz SOURCE
    gload_lds16(A + (size_t)row * HID + kt + sl * 8, la + ((i * 256 + w * 64) << 3));
    gload_lds16(B + (size_t)row * HID + kt + sl * 8, lb + ((i * 256 + w * 64) << 3));
  }
}

__global__ __launch_bounds__(256) void gemm_qkv_kernel(
    const unsigned short* __restrict__ Xq, const unsigned short* __restrict__ Xk,
    const unsigned short* __restrict__ Xv, const unsigned short* __restrict__ Wt,
    const float* __restrict__ bq, const float* __restrict__ bk,
    const float* __restrict__ bv, unsigned short* __restrict__ QKV) {
  __shared__ __align__(16) unsigned short lA[2][128 * 32];
  __shared__ __align__(16) unsigned short lB[2][128 * 32];
  int z = blockIdx.z;
  const unsigned short* Ain = z == 0 ? Xq : (z == 1 ? Xk : Xv);
  const float* bias = z == 0 ? bq : (z == 1 ? bk : bv);
  float scale = z == 0 ? 0.125f * L2E : 1.0f;
  int m0 = blockIdx.x * 128, n0 = blockIdx.y * 128;
  const unsigned short* A = Ain + (size_t)m0 * HID;
  const unsigned short* B = Wt + (size_t)z * (HID * HID) + (size_t)n0 * HID;
  unsigned short* Out = QKV + (size_t)z * ((size_t)MROWS * 1024);

  f32x4_t acc[4][4] = {};
  int tid = threadIdx.x, lane = tid & 63, w = tid >> 6;
  int wr = (w >> 1) << 6, wc = (w & 1) << 6;
  int ql = lane & 15, g = lane >> 4;

  gemm_stage32(A, B, lA[0], lB[0], tid, w, 0);
  __syncthreads();
  int cur = 0;
  for (int kt = 0; kt < HID; kt += 32) {
    if (kt + 32 < HID)
      gemm_stage32(A, B, lA[cur ^ 1], lB[cur ^ 1], tid, w, kt + 32);
    const unsigned short* la = lA[cur];
    const unsigned short* lb = lB[cur];
    bf16x8_t af[4], bfr[4];
#pragma unroll
    for (int mi = 0; mi < 4; ++mi)
      af[mi] = frag_ld32(la, wr + mi * 16 + ql, g);
#pragma unroll
    for (int ni = 0; ni < 4; ++ni)
      bfr[ni] = frag_ld32(lb, wc + ni * 16 + ql, g);
#pragma unroll
    for (int mi = 0; mi < 4; ++mi)
#pragma unroll
      for (int ni = 0; ni < 4; ++ni)
        acc[mi][ni] = __builtin_amdgcn_mfma_f32_16x16x32_bf16(af[mi], bfr[ni],
                                                              acc[mi][ni], 0, 0, 0);
    __syncthreads();
    cur ^= 1;
  }

  if (z < 2) {
    // standard [b][h][s][64] store (Q scaled, K unscaled)
#pragma unroll
    for (int mi = 0; mi < 4; ++mi)
#pragma unroll
      for (int ni = 0; ni < 4; ++ni) {
        int col = n0 + wc + ni * 16 + ql;
        float bb = bias[col];
        int h = col >> 6, d = col & 63;
#pragma unroll
        for (int r = 0; r < 4; ++r) {
          int row = m0 + wr + mi * 16 + (g << 2) + r;
          int b = row >> 11, s = row & 2047;
          Out[((((size_t)b * NH + h) * SLEN + s) << 6) + d] =
              bfbits((acc[mi][ni][r] + bb) * scale);
        }
      }
  } else {
    // V: transpose in wave-private 8KB LDS (post-barrier reuse of lA/lB),
    // then coalesced store as VT[bh][dv][s].
    unsigned short* tb = (w < 2) ? lA[w] : lB[w - 2];  // [64 d][32 u32] region
    unsigned int* tu = (unsigned int*)tb;
#pragma unroll
    for (int mi = 0; mi < 4; ++mi)
#pragma unroll
      for (int ni = 0; ni < 4; ++ni) {
        int col = n0 + wc + ni * 16 + ql;
        float bb = bias[col];
        int dl = ni * 16 + ql;                 // d_local 0..63
        int sp0 = 8 * mi + 2 * g;              // s-pair index (even)
        unsigned int v0 = packbf(acc[mi][ni][0] + bb, acc[mi][ni][1] + bb);
        unsigned int v1 = packbf(acc[mi][ni][2] + bb, acc[mi][ni][3] + bb);
        int slot = (sp0 >> 2) ^ (dl & 7);      // sp0,sp0+1 share this slot
        *(uint2*)(tu + dl * 32 + slot * 4 + (sp0 & 3)) = make_uint2(v0, v1);
      }
    int srow = m0 + wr;                        // 64-aligned: single batch
    int b = srow >> 11, sl_ = srow & 2047;
    int h = (n0 + wc) >> 6;                    // 64-aligned cols: single head
    unsigned short* VTo = Out + (((size_t)(b * NH + h) * 64) * SLEN);
#pragma unroll
    for (int pass = 0; pass < 8; ++pass) {
      int dl = (lane >> 3) + 8 * pass;
      int slot = lane & 7;
      uint4 vv = *(const uint4*)(tu + dl * 32 + ((slot ^ (dl & 7)) << 2));
      *(uint4*)(VTo + (size_t)dl * SLEN + sl_ + slot * 8) = vv;
    }
  }
}

// ---- output projection GEMM: champion BK=64 2-phase -------------------------
__device__ __forceinline__ void gemm_stage(const unsigned short* __restrict__ A,
    const unsigned short* __restrict__ B, unsigned short* la, unsigned short* lb,
    int tid, int w, int kt) {
#pragma unroll
  for (int i = 0; i < 4; ++i) {
    int flat = i * 256 + tid;
    int row = flat >> 3;
    int sl = (flat & 7) ^ (row & 7);
    gload_lds16(A + (size_t)row * HID + kt + sl * 8, la + ((i * 256 + w * 64) << 3));
    gload_lds16(B + (size_t)row * HID + kt + sl * 8, lb + ((i * 256 + w * 64) << 3));
  }
}

__global__ __launch_bounds__(256) void gemm_out_kernel(
    const unsigned short* __restrict__ Ob, const unsigned short* __restrict__ WoT,
    const float* __restrict__ bo, float* __restrict__ out) {
  __shared__ __align__(16) unsigned short lA[2][128 * 64];
  __shared__ __align__(16) unsigned short lB[2][128 * 64];
  int m0 = blockIdx.x * 128, n0 = blockIdx.y * 128;
  const unsigned short* A = Ob + (size_t)m0 * HID;
  const unsigned short* B = WoT + (size_t)n0 * HID;
  f32x4_t acc[4][4] = {};
  int tid = threadIdx.x;
  int lane = tid & 63, w = tid >> 6;
  int wr = (w >> 1) << 6, wc = (w & 1) << 6;
  gemm_stage(A, B, lA[0], lB[0], tid, w, 0);
  __syncthreads();
  int cur = 0;
  for (int kt = 0; kt < HID; kt += 64) {
    if (kt + 64 < HID)
      gemm_stage(A, B, lA[cur ^ 1], lB[cur ^ 1], tid, w, kt + 64);
    const unsigned short* la = lA[cur];
    const unsigned short* lb = lB[cur];
#pragma unroll
    for (int kk = 0; kk < 2; ++kk) {
      bf16x8_t af[4], bfr[4];
#pragma unroll
      for (int mi = 0; mi < 4; ++mi)
        af[mi] = frag_ld(la, wr + mi * 16 + (lane & 15), kk * 4 + (lane >> 4));
#pragma unroll
      for (int ni = 0; ni < 4; ++ni)
        bfr[ni] = frag_ld(lb, wc + ni * 16 + (lane & 15), kk * 4 + (lane >> 4));
#pragma unroll
      for (int mi = 0; mi < 4; ++mi)
#pragma unroll
        for (int ni = 0; ni < 4; ++ni)
          acc[mi][ni] = __builtin_amdgcn_mfma_f32_16x16x32_bf16(af[mi], bfr[ni],
                                                                acc[mi][ni], 0, 0, 0);
    }
    __syncthreads();
    cur ^= 1;
  }
#pragma unroll
  for (int mi = 0; mi < 4; ++mi)
#pragma unroll
    for (int ni = 0; ni < 4; ++ni) {
      int col = n0 + wc + ni * 16 + (lane & 15);
      float bb = bo[col];
#pragma unroll
      for (int r = 0; r < 4; ++r) {
        int row = m0 + wr + mi * 16 + ((lane >> 4) << 2) + r;
        out[(size_t)row * HID + col] = acc[mi][ni][r] + bb;
      }
    }
}

// ---- flash attention: swapped QK^T, static-max softmax, register-P PV -------
// KVBLK=128: two 64-kv halves per barrier (champion per-half body verbatim).
__global__ __launch_bounds__(256) void attn_kernel(
    const unsigned short* __restrict__ Q, const unsigned short* __restrict__ K,
    const unsigned short* __restrict__ VT, const unsigned long long* __restrict__ mbits,
    unsigned short* __restrict__ O) {
  __shared__ __align__(16) unsigned short lK[2][2][64 * 64];  // [buf][half][kv][d]
  __shared__ __align__(16) unsigned short lV[2][2][64 * 64];  // [buf][half][dv][kv]
  int tid = threadIdx.x, lane = tid & 63, w = tid >> 6;
  int g = lane >> 4, ql = lane & 15;
  int bid = blockIdx.x;
  int bh = (bid & 7) * 8 + ((bid >> 3) >> 4);
  int qt = (bid >> 3) & 15;
  int b = bh >> 4, h = bh & 15;
  int q0 = qt * 128;
  const unsigned short* Qb = Q + (size_t)bh * (SLEN * 64);

  // hoisted staging source pointers (per thread), bumped per 128-kv tile
  int f0 = tid, f1 = 256 + tid;
  int r0 = f0 >> 3, r1 = f1 >> 3;
  int s0 = (f0 & 7) ^ (r0 & 7), s1 = (f1 & 7) ^ (r1 & 7);
  const unsigned short* kS0 = K + (size_t)bh * (SLEN * 64) + (size_t)r0 * 64 + s0 * 8;
  const unsigned short* kS1 = K + (size_t)bh * (SLEN * 64) + (size_t)r1 * 64 + s1 * 8;
  const unsigned short* vS0 = VT + (size_t)bh * (64 * SLEN) + (size_t)r0 * SLEN + s0 * 8;
  const unsigned short* vS1 = VT + (size_t)bh * (64 * SLEN) + (size_t)r1 * SLEN + s1 * 8;
  int d0off = (0 * 256 + w * 64) << 3;
  int d1off = (1 * 256 + w * 64) << 3;
  // hoisted mask row pointers (indexed by 64-kv word: 2*kt + half)
  const unsigned long long* mp0 = mbits + ((size_t)b * SLEN + (q0 + w * 32 + ql)) * 32;
  const unsigned long long* mp1 = mp0 + 16 * 32;

  // V-frag read base (byte) within a [64][64] half: chunk c via ^ (c<<5)
  int vbyte0 = (ql << 7) + (((g >> 1) ^ (ql & 7)) << 4) + ((g & 1) << 3);

  // Q fragments in registers (wave owns 32 q rows; Q pre-scaled by 0.125*L2E)
  bf16x8_t qf[2][2];
#pragma unroll
  for (int mi = 0; mi < 2; ++mi)
#pragma unroll
    for (int kk = 0; kk < 2; ++kk) {
      int row = q0 + w * 32 + mi * 16 + ql;
      qf[mi][kk] = *(const bf16x8_t*)(Qb + (size_t)row * 64 + kk * 32 + g * 8);
    }

  s16x4_t ones4 = {0x3F80, 0x3F80, 0x3F80, 0x3F80};  // 4x bf16 1.0

  f32x4_t aco[2][4] = {};     // O^T: dv=dvf*16+4g+r, q=mi*16+ql
  f32x4_t slacc[2] = {};      // l[q=ql] via ones-MFMA

  // ---- prologue: stage 128-kv tile 0 (both halves) ----
#pragma unroll
  for (int hh = 0; hh < 2; ++hh) {
    gload_lds16(kS0 + hh * 4096, (unsigned short*)lK[0][hh] + d0off);
    gload_lds16(kS1 + hh * 4096, (unsigned short*)lK[0][hh] + d1off);
    gload_lds16(vS0 + hh * 64,   (unsigned short*)lV[0][hh] + d0off);
    gload_lds16(vS1 + hh * 64,   (unsigned short*)lV[0][hh] + d1off);
  }
  kS0 += 8192; kS1 += 8192; vS0 += 128; vS1 += 128;
  __syncthreads();

  int cur = 0;
  for (int kt = 0; kt < SLEN / 128; ++kt) {
    // ---- issue next 128-kv tile staging (hides under this tile's compute) ----
    if (kt + 1 < SLEN / 128) {
#pragma unroll
      for (int hh = 0; hh < 2; ++hh) {
        gload_lds16(kS0 + hh * 4096, (unsigned short*)lK[cur ^ 1][hh] + d0off);
        gload_lds16(kS1 + hh * 4096, (unsigned short*)lK[cur ^ 1][hh] + d1off);
        gload_lds16(vS0 + hh * 64,   (unsigned short*)lV[cur ^ 1][hh] + d0off);
        gload_lds16(vS1 + hh * 64,   (unsigned short*)lV[cur ^ 1][hh] + d1off);
      }
      kS0 += 8192; kS1 += 8192; vS0 += 128; vS1 += 128;
    }

#pragma unroll
    for (int hh = 0; hh < 2; ++hh) {
      // ---- mask bits for this half ----
      unsigned long long bg0 = mp0[2 * kt + hh] >> (4 * g);
      unsigned long long bg1 = mp1[2 * kt + hh] >> (4 * g);

      const unsigned short* kbuf = lK[cur][hh];
      const unsigned short* vbuf = lV[cur][hh];

      // ---- QK^T swapped: st[mi][ni][r] = S_log2[kv=ni*16+4g+r][q] ----
      f32x4_t st[2][4];
#pragma unroll
      for (int mi = 0; mi < 2; ++mi)
#pragma unroll
        for (int ni = 0; ni < 4; ++ni) st[mi][ni] = (f32x4_t){0.f, 0.f, 0.f, 0.f};
      __builtin_amdgcn_s_setprio(1);
#pragma unroll
      for (int kk = 0; kk < 2; ++kk) {
        bf16x8_t kf[4];
#pragma unroll
        for (int ni = 0; ni < 4; ++ni)
          kf[ni] = frag_ld(kbuf, ni * 16 + ql, kk * 4 + g);
#pragma unroll
        for (int mi = 0; mi < 2; ++mi)
#pragma unroll
          for (int ni = 0; ni < 4; ++ni)
            st[mi][ni] = __builtin_amdgcn_mfma_f32_16x16x32_bf16(kf[ni], qf[mi][kk],
                                                                 st[mi][ni], 0, 0, 0);
      }
      __builtin_amdgcn_s_setprio(0);

      // ---- static-max softmax: p = mask ? 2^st : 0, packed IN REGISTERS ----
      unsigned int pb[2][4][2];
#pragma unroll
      for (int mi = 0; mi < 2; ++mi) {
        unsigned long long bgs = mi ? bg1 : bg0;
        unsigned int mw0 = (unsigned int)bgs;          // ni 0,1 bits
        unsigned int mw1 = (unsigned int)(bgs >> 32);  // ni 2,3 bits
#pragma unroll
        for (int ni = 0; ni < 4; ++ni) {
          unsigned int mword = (ni < 2) ? mw0 : mw1;
          int base = (ni & 1) * 16;
          float p[4];
#pragma unroll
          for (int r = 0; r < 4; ++r) {
            float e = fast_exp2(st[mi][ni][r]);
            p[r] = ((mword >> (base + r)) & 1u) ? e : 0.f;
          }
          pb[mi][ni][0] = packbf(p[0], p[1]);
          pb[mi][ni][1] = packbf(p[2], p[3]);
        }
      }

      // ---- PV as O^T via 16x16x16 MFMA: P^T regs are the B-operand ----
      __builtin_amdgcn_s_setprio(1);
#pragma unroll
      for (int c = 0; c < 4; ++c) {
        s16x4_t vfa[4];
#pragma unroll
        for (int dvf = 0; dvf < 4; ++dvf) {
          union { uint2 u; s16x4_t s; } t;
          t.u = *(const uint2*)((const char*)vbuf + ((vbyte0 ^ (c << 5)) + dvf * 2048));
          vfa[dvf] = t.s;
        }
#pragma unroll
        for (int mi = 0; mi < 2; ++mi) {
          union { unsigned int u[2]; s16x4_t s; } pp;
          pp.u[0] = pb[mi][c][0]; pp.u[1] = pb[mi][c][1];
          slacc[mi] = mfma16x16(ones4, pp.s, slacc[mi]);
#pragma unroll
          for (int dvf = 0; dvf < 4; ++dvf)
            aco[mi][dvf] = mfma16x16(vfa[dvf], pp.s, aco[mi][dvf]);
        }
      }
      __builtin_amdgcn_s_setprio(0);
    }

    __syncthreads();  // drains vmcnt (K/V prefetch); releases buffers
    cur ^= 1;
  }

  // epilogue: normalize O^T, transpose through lK scratch (wave-private rows)
  unsigned short* eb = (unsigned short*)lK;  // 32KB avail, need 16KB [128][128B]
#pragma unroll
  for (int mi = 0; mi < 2; ++mi) {
    float inv = 1.0f / slacc[mi][0];
    int prow = w * 32 + mi * 16 + ql;
#pragma unroll
    for (int dvf = 0; dvf < 4; ++dvf) {
      unsigned int lo = packbf(aco[mi][dvf][0] * inv, aco[mi][dvf][1] * inv);
      unsigned int hi = packbf(aco[mi][dvf][2] * inv, aco[mi][dvf][3] * inv);
      int sl = (2 * dvf + (g >> 1)) ^ (prow & 7);
      *(uint2*)((char*)eb + prow * 128 + sl * 16 + (g & 1) * 8) = make_uint2(lo, hi);
    }
  }
#pragma unroll
  for (int it = 0; it < 8; ++it) {
    int rloc = g + 4 * it;
    int row = w * 32 + rloc;
    int sl = (ql >> 1) ^ (row & 7);
    uint2 v = *(const uint2*)((const char*)eb + row * 128 + sl * 16 + (ql & 1) * 8);
    int qrow = q0 + row;
    *(uint2*)(O + (((size_t)b * SLEN + qrow) << 10) + h * 64 + ql * 4) = v;
  }
}

// ---------------------------------------------------------------------------
extern "C" void kernel_launch(void* const* d_in, const int* in_sizes, int n_in,
                              void* d_out, int out_size, void* d_ws, size_t ws_size,
                              hipStream_t stream) {
  (void)in_sizes; (void)n_in; (void)out_size; (void)ws_size;
  const float* xq = (const float*)d_in[0];
  const float* xk = (const float*)d_in[1];
  const float* xv = (const float*)d_in[2];
  const void*  mask = d_in[3];
  const float* wq = (const float*)d_in[4];
  const float* bq = (const float*)d_in[5];
  const float* wk = (const float*)d_in[6];
  const float* bk = (const float*)d_in[7];
  const float* wv = (const float*)d_in[8];
  const float* bv = (const float*)d_in[9];
  const float* wo = (const float*)d_in[10];
  const float* bo = (const float*)d_in[11];
  float* out = (float*)d_out;

  char* ws = (char*)d_ws;
  unsigned short* Xq   = (unsigned short*)(ws);                   // 16 MiB, later Ob
  unsigned short* Ob   = (unsigned short*)(ws);                   // overlays Xq
  unsigned short* Wt   = (unsigned short*)(ws + 16777216ull);     // 8 MiB packed weights
  unsigned short* QKV  = (unsigned short*)(ws + 25165824ull);     // 48 MiB
  unsigned int*   flag = (unsigned int*)(ws + 75497472ull);       // 4 B
  // d_out overlay (32 MiB): qkv phase Xk [0,16M), Xv [16,32M);
  // afterwards bitmask [16M,18M). gemm_out overwrites at the end.
  unsigned short* Xk  = (unsigned short*)d_out;
  unsigned short* Xv  = (unsigned short*)((char*)d_out + 16777216ull);
  unsigned long long* mbits = (unsigned long long*)((char*)d_out + 16777216ull);

  detect_mask_kernel<<<1, 256, 0, stream>>>((const unsigned int*)mask, flag);
  pack_w_kernel<<<dim3(1024, 4), 256, 0, stream>>>(wq, wk, wv, wo, Wt);
  cvt_x_kernel<<<dim3(8192, 3), 256, 0, stream>>>(xq, xk, xv, Xq, Xk, Xv);
  gemm_qkv_kernel<<<dim3(64, 8, 3), 256, 0, stream>>>(Xq, Xk, Xv, Wt, bq, bk, bv, QKV);
  mask_bits_kernel<<<4096, 256, 0, stream>>>(mask, flag, mbits);   // Xv region now dead
  attn_kernel<<<1024, 256, 0, stream>>>(QKV, QKV + 8388608ull,
                                        QKV + 16777216ull, mbits, Ob);  // Xq dead
  gemm_out_kernel<<<dim3(64, 8), 256, 0, stream>>>(Ob, Wt + 3ull * (HID * HID), bo, out);
}

// Round 18
// 289.766 us; speedup vs baseline: 1.0406x; 1.0072x over previous
//
#include <hip/hip_runtime.h>
#include <stdint.h>

// ---------------------------------------------------------------------------
// MHA: B=4 S=2048 H=16 Dk=Dv=64 HIDDEN=1024, fp32 in/out, bf16 MFMA compute.
// Pipeline: detect -> pack_w -> cvt_x(all 3) -> gemm_qkv(MERGED z, BK=32,
//           z=2 writes V TRANSPOSED in-epilogue) -> mask_bits -> attn -> gemm_out
// Round 18: attn QBLK 128 -> 256 (8 waves, 512 threads). K/V LDS footprint is
// q-independent, so LDS stays 64KB -> still 2 blocks/CU but 16 waves/CU (2x
// latency hiding for the measured ~2100cy/iter exposed drain). K/V staged half
// as often (512 vs 1024 blocks) -> attn FETCH -25%; 4 gloads/thread/tile.
// Per-wave body = round-17 champion verbatim (KVBLK=128, two halves/barrier).
// Scratch ws (72 MiB + 4B):
//   [0,16MiB)   Xq (bf16) ... later reused as Ob (attn out)
//   [16,24MiB)  Wt  (packed bf16 weights, 4x 1024x1024, N-major)
//   [24,72MiB)  QKV (bf16): z=0 Q, z=1 K (std [bh][s][64]); z=2 VT [bh][dv][s]
//   @72MiB      mask-dtype flag (4B)
// d_out overlay (32 MiB): qkv phase: Xk [0,16), Xv [16,32);
//   after: bitmask [16,18). gemm_out overwrites all at the end.
// ---------------------------------------------------------------------------

typedef __bf16 bf16x8_t __attribute__((ext_vector_type(8)));
typedef float f32x4_t __attribute__((ext_vector_type(4)));
typedef short s16x4_t __attribute__((ext_vector_type(4)));

#define HID   1024
#define SLEN  2048
#define BATCH 4
#define NH    16
#define MROWS 8192   // BATCH*SLEN
#define L2E   1.44269504f

__device__ __forceinline__ unsigned short bfbits(float f) {
  union { __bf16 h; unsigned short u; } v; v.h = (__bf16)f; return v.u;
}
__device__ __forceinline__ unsigned int packbf(float a, float b) {
  return (unsigned int)bfbits(a) | ((unsigned int)bfbits(b) << 16);
}
__device__ __forceinline__ float fast_exp2(float x) {
#if __has_builtin(__builtin_amdgcn_exp2f)
  return __builtin_amdgcn_exp2f(x);
#else
  return __exp2f(x);
#endif
}

__device__ __forceinline__ f32x4_t mfma16x16(s16x4_t a, s16x4_t b, f32x4_t c) {
#if __has_builtin(__builtin_amdgcn_mfma_f32_16x16x16bf16_1k)
  return __builtin_amdgcn_mfma_f32_16x16x16bf16_1k(a, b, c, 0, 0, 0);
#else
  asm("v_mfma_f32_16x16x16_bf16 %0, %1, %2, %0" : "+v"(c) : "v"(a), "v"(b));
  return c;
#endif
}

__device__ __forceinline__ void gload_lds16(const void* g, void* l) {
  __builtin_amdgcn_global_load_lds((const __attribute__((address_space(1))) void*)g,
                                   (__attribute__((address_space(3))) void*)l,
                                   16, 0, 0);
}

// 64-wide LDS rows (128B, 8 slots of 16B): physical slot = logical ^ (row & 7)
__device__ __forceinline__ bf16x8_t frag_ld(const unsigned short* lds, int row, int sblk) {
  int sp = sblk ^ (row & 7);
  return *(const bf16x8_t*)(lds + (row << 6) + (sp << 3));
}
// 32-wide LDS rows (64B, 4 slots of 16B): slot = logical ^ (row&3) ^ ((row>>2)&3)
__device__ __forceinline__ bf16x8_t frag_ld32(const unsigned short* lds, int row, int g) {
  int sp = g ^ (row & 3) ^ ((row >> 2) & 3);
  return *(const bf16x8_t*)(lds + (row << 5) + (sp << 3));
}

// ---- mask dtype detector: bool bytes (1B) vs int32 --------------------------
__global__ void detect_mask_kernel(const unsigned int* __restrict__ m,
                                   unsigned int* __restrict__ flag) {
  unsigned int v = m[threadIdx.x];
  unsigned long long b = __ballot(v > 1u);         // packed bools give words > 1
  if (threadIdx.x == 0) flag[0] = 0u;
  __syncthreads();
  if ((threadIdx.x & 63) == 0 && b) atomicOr(flag, 1u);  // 1 => byte mask
}

// ---- mask -> bitmask: bits[(b*S+q)*32 + kw] bit i = mask[b][q][kw*64+i] -----
__global__ __launch_bounds__(256) void mask_bits_kernel(const void* __restrict__ maskp,
    const unsigned int* __restrict__ flag, unsigned long long* __restrict__ bits) {
  int lane = threadIdx.x & 63, wv = threadIdx.x >> 6;
  bool bytemask = flag[0] != 0u;
  size_t w0 = (size_t)blockIdx.x * 64 + (size_t)wv * 16;
  for (int it = 0; it < 16; ++it) {
    size_t word = w0 + it;
    unsigned int v;
    if (bytemask) v = ((const unsigned char*)maskp)[word * 64 + lane];
    else          v = ((const unsigned int*)maskp)[word * 64 + lane];
    unsigned long long bm = __ballot(v != 0u);
    if (lane == 0) bits[word] = bm;
  }
}

// ---- fp32 -> bf16 conversion of all three hidden inputs ---------------------
__global__ __launch_bounds__(256) void cvt_x_kernel(const float* __restrict__ xq,
    const float* __restrict__ xk, const float* __restrict__ xv,
    unsigned short* __restrict__ dq, unsigned short* __restrict__ dk,
    unsigned short* __restrict__ dv) {
  int z = blockIdx.y;
  const float* src = z == 0 ? xq : (z == 1 ? xk : xv);
  unsigned short* dst = z == 0 ? dq : (z == 1 ? dk : dv);
  size_t base = (size_t)blockIdx.x * 1024 + (size_t)threadIdx.x * 4;
  float4 v = *(const float4*)(src + base);
  ushort4 o;
  o.x = bfbits(v.x); o.y = bfbits(v.y); o.z = bfbits(v.z); o.w = bfbits(v.w);
  *(ushort4*)(dst + base) = o;
}

// ---- pack weights into bf16, N-major: Wt[z][n][k] ---------------------------
__global__ __launch_bounds__(256) void pack_w_kernel(const float* __restrict__ wq,
    const float* __restrict__ wk, const float* __restrict__ wv,
    const float* __restrict__ wo, unsigned short* __restrict__ wt) {
  int z = blockIdx.y;
  int id = blockIdx.x * 256 + threadIdx.x;
  int n = id >> 8;
  int d0 = (id & 255) << 2;
  ushort4 o;
  if (z < 3) {
    const float* w = z == 0 ? wq : (z == 1 ? wk : wv);
    const float* base = w + (size_t)(n >> 6) * (HID * 64) + (n & 63);
    o.x = bfbits(base[(size_t)(d0 + 0) * 64]);
    o.y = bfbits(base[(size_t)(d0 + 1) * 64]);
    o.z = bfbits(base[(size_t)(d0 + 2) * 64]);
    o.w = bfbits(base[(size_t)(d0 + 3) * 64]);
  } else {
    o.x = bfbits(wo[(size_t)(d0 + 0) * HID + n]);
    o.y = bfbits(wo[(size_t)(d0 + 1) * HID + n]);
    o.z = bfbits(wo[(size_t)(d0 + 2) * HID + n]);
    o.w = bfbits(wo[(size_t)(d0 + 3) * HID + n]);
  }
  *(ushort4*)(wt + (size_t)z * (HID * HID) + (size_t)n * HID + d0) = o;
}

// ---- MERGED QKV GEMM: 128x128 tile, BK=32, dbuf LDS 32KB --------------------
__device__ __forceinline__ void gemm_stage32(const unsigned short* __restrict__ A,
    const unsigned short* __restrict__ B, unsigned short* la, unsigned short* lb,
    int tid, int w, int kt) {
#pragma unroll
  for (int i = 0; i < 2; ++i) {
    int flat = i * 256 + tid;
    int row = flat >> 2;
    int sl = (flat & 3) ^ (row & 3) ^ ((row >> 2) & 3);  // inverse-swz SOURCE
    gload_lds16(A + (size_t)row * HID + kt + sl * 8, la + ((i * 256 + w * 64) << 3));
    gload_lds16(B + (size_t)row * HID + kt + sl * 8, lb + ((i * 256 + w * 64) << 3));
  }
}

__global__ __launch_bounds__(256) void gemm_qkv_kernel(
    const unsigned short* __restrict__ Xq, const unsigned short* __restrict__ Xk,
    const unsigned short* __restrict__ Xv, const unsigned short* __restrict__ Wt,
    const float* __restrict__ bq, const float* __restrict__ bk,
    const float* __restrict__ bv, unsigned short* __restrict__ QKV) {
  __shared__ __align__(16) unsigned short lA[2][128 * 32];
  __shared__ __align__(16) unsigned short lB[2][128 * 32];
  int z = blockIdx.z;
  const unsigned short* Ain = z == 0 ? Xq : (z == 1 ? Xk : Xv);
  const float* bias = z == 0 ? bq : (z == 1 ? bk : bv);
  float scale = z == 0 ? 0.125f * L2E : 1.0f;
  int m0 = blockIdx.x * 128, n0 = blockIdx.y * 128;
  const unsigned short* A = Ain + (size_t)m0 * HID;
  const unsigned short* B = Wt + (size_t)z * (HID * HID) + (size_t)n0 * HID;
  unsigned short* Out = QKV + (size_t)z * ((size_t)MROWS * 1024);

  f32x4_t acc[4][4] = {};
  int tid = threadIdx.x, lane = tid & 63, w = tid >> 6;
  int wr = (w >> 1) << 6, wc = (w & 1) << 6;
  int ql = lane & 15, g = lane >> 4;

  gemm_stage32(A, B, lA[0], lB[0], tid, w, 0);
  __syncthreads();
  int cur = 0;
  for (int kt = 0; kt < HID; kt += 32) {
    if (kt + 32 < HID)
      gemm_stage32(A, B, lA[cur ^ 1], lB[cur ^ 1], tid, w, kt + 32);
    const unsigned short* la = lA[cur];
    const unsigned short* lb = lB[cur];
    bf16x8_t af[4], bfr[4];
#pragma unroll
    for (int mi = 0; mi < 4; ++mi)
      af[mi] = frag_ld32(la, wr + mi * 16 + ql, g);
#pragma unroll
    for (int ni = 0; ni < 4; ++ni)
      bfr[ni] = frag_ld32(lb, wc + ni * 16 + ql, g);
#pragma unroll
    for (int mi = 0; mi < 4; ++mi)
#pragma unroll
      for (int ni = 0; ni < 4; ++ni)
        acc[mi][ni] = __builtin_amdgcn_mfma_f32_16x16x32_bf16(af[mi], bfr[ni],
                                                              acc[mi][ni], 0, 0, 0);
    __syncthreads();
    cur ^= 1;
  }

  if (z < 2) {
#pragma unroll
    for (int mi = 0; mi < 4; ++mi)
#pragma unroll
      for (int ni = 0; ni < 4; ++ni) {
        int col = n0 + wc + ni * 16 + ql;
        float bb = bias[col];
        int h = col >> 6, d = col & 63;
#pragma unroll
        for (int r = 0; r < 4; ++r) {
          int row = m0 + wr + mi * 16 + (g << 2) + r;
          int b = row >> 11, s = row & 2047;
          Out[((((size_t)b * NH + h) * SLEN + s) << 6) + d] =
              bfbits((acc[mi][ni][r] + bb) * scale);
        }
      }
  } else {
    // V: transpose in wave-private 8KB LDS, store as VT[bh][dv][s]
    unsigned short* tb = (w < 2) ? lA[w] : lB[w - 2];
    unsigned int* tu = (unsigned int*)tb;
#pragma unroll
    for (int mi = 0; mi < 4; ++mi)
#pragma unroll
      for (int ni = 0; ni < 4; ++ni) {
        int col = n0 + wc + ni * 16 + ql;
        float bb = bias[col];
        int dl = ni * 16 + ql;
        int sp0 = 8 * mi + 2 * g;
        unsigned int v0 = packbf(acc[mi][ni][0] + bb, acc[mi][ni][1] + bb);
        unsigned int v1 = packbf(acc[mi][ni][2] + bb, acc[mi][ni][3] + bb);
        int slot = (sp0 >> 2) ^ (dl & 7);
        *(uint2*)(tu + dl * 32 + slot * 4 + (sp0 & 3)) = make_uint2(v0, v1);
      }
    int srow = m0 + wr;
    int b = srow >> 11, sl_ = srow & 2047;
    int h = (n0 + wc) >> 6;
    unsigned short* VTo = Out + (((size_t)(b * NH + h) * 64) * SLEN);
#pragma unroll
    for (int pass = 0; pass < 8; ++pass) {
      int dl = (lane >> 3) + 8 * pass;
      int slot = lane & 7;
      uint4 vv = *(const uint4*)(tu + dl * 32 + ((slot ^ (dl & 7)) << 2));
      *(uint4*)(VTo + (size_t)dl * SLEN + sl_ + slot * 8) = vv;
    }
  }
}

// ---- output projection GEMM: champion BK=64 2-phase -------------------------
__device__ __forceinline__ void gemm_stage(const unsigned short* __restrict__ A,
    const unsigned short* __restrict__ B, unsigned short* la, unsigned short* lb,
    int tid, int w, int kt) {
#pragma unroll
  for (int i = 0; i < 4; ++i) {
    int flat = i * 256 + tid;
    int row = flat >> 3;
    int sl = (flat & 7) ^ (row & 7);
    gload_lds16(A + (size_t)row * HID + kt + sl * 8, la + ((i * 256 + w * 64) << 3));
    gload_lds16(B + (size_t)row * HID + kt + sl * 8, lb + ((i * 256 + w * 64) << 3));
  }
}

__global__ __launch_bounds__(256) void gemm_out_kernel(
    const unsigned short* __restrict__ Ob, const unsigned short* __restrict__ WoT,
    const float* __restrict__ bo, float* __restrict__ out) {
  __shared__ __align__(16) unsigned short lA[2][128 * 64];
  __shared__ __align__(16) unsigned short lB[2][128 * 64];
  int m0 = blockIdx.x * 128, n0 = blockIdx.y * 128;
  const unsigned short* A = Ob + (size_t)m0 * HID;
  const unsigned short* B = WoT + (size_t)n0 * HID;
  f32x4_t acc[4][4] = {};
  int tid = threadIdx.x;
  int lane = tid & 63, w = tid >> 6;
  int wr = (w >> 1) << 6, wc = (w & 1) << 6;
  gemm_stage(A, B, lA[0], lB[0], tid, w, 0);
  __syncthreads();
  int cur = 0;
  for (int kt = 0; kt < HID; kt += 64) {
    if (kt + 64 < HID)
      gemm_stage(A, B, lA[cur ^ 1], lB[cur ^ 1], tid, w, kt + 64);
    const unsigned short* la = lA[cur];
    const unsigned short* lb = lB[cur];
#pragma unroll
    for (int kk = 0; kk < 2; ++kk) {
      bf16x8_t af[4], bfr[4];
#pragma unroll
      for (int mi = 0; mi < 4; ++mi)
        af[mi] = frag_ld(la, wr + mi * 16 + (lane & 15), kk * 4 + (lane >> 4));
#pragma unroll
      for (int ni = 0; ni < 4; ++ni)
        bfr[ni] = frag_ld(lb, wc + ni * 16 + (lane & 15), kk * 4 + (lane >> 4));
#pragma unroll
      for (int mi = 0; mi < 4; ++mi)
#pragma unroll
        for (int ni = 0; ni < 4; ++ni)
          acc[mi][ni] = __builtin_amdgcn_mfma_f32_16x16x32_bf16(af[mi], bfr[ni],
                                                                acc[mi][ni], 0, 0, 0);
    }
    __syncthreads();
    cur ^= 1;
  }
#pragma unroll
  for (int mi = 0; mi < 4; ++mi)
#pragma unroll
    for (int ni = 0; ni < 4; ++ni) {
      int col = n0 + wc + ni * 16 + (lane & 15);
      float bb = bo[col];
#pragma unroll
      for (int r = 0; r < 4; ++r) {
        int row = m0 + wr + mi * 16 + ((lane >> 4) << 2) + r;
        out[(size_t)row * HID + col] = acc[mi][ni][r] + bb;
      }
    }
}

// ---- flash attention: swapped QK^T, static-max softmax, register-P PV -------
// QBLK=256 (8 waves), KVBLK=128 (two 64-kv halves per barrier).
__global__ __launch_bounds__(512) void attn_kernel(
    const unsigned short* __restrict__ Q, const unsigned short* __restrict__ K,
    const unsigned short* __restrict__ VT, const unsigned long long* __restrict__ mbits,
    unsigned short* __restrict__ O) {
  __shared__ __align__(16) unsigned short lK[2][2][64 * 64];  // [buf][half][kv][d]
  __shared__ __align__(16) unsigned short lV[2][2][64 * 64];  // [buf][half][dv][kv]
  int tid = threadIdx.x, lane = tid & 63, w = tid >> 6;       // w in 0..7
  int g = lane >> 4, ql = lane & 15;
  int bid = blockIdx.x;                         // 512 blocks = 8 qt x 64 bh
  int bh = (bid & 7) * 8 + ((bid >> 3) >> 3);   // XCD-grouped, bijective
  int qt = (bid >> 3) & 7;
  int b = bh >> 4, h = bh & 15;
  int q0 = qt * 256;
  const unsigned short* Qb = Q + (size_t)bh * (SLEN * 64);

  // staging: 512 threads, 1 gload per K-half and V-half each (8KB per half)
  int r0 = tid >> 3;
  int s0 = (tid & 7) ^ (r0 & 7);
  const unsigned short* kS0 = K + (size_t)bh * (SLEN * 64) + (size_t)r0 * 64 + s0 * 8;
  const unsigned short* vS0 = VT + (size_t)bh * (64 * SLEN) + (size_t)r0 * SLEN + s0 * 8;
  int doff = tid << 3;   // dest = base + tid*8 shorts (wave-uniform base + lane*16B)
  // hoisted mask row pointers (indexed by 64-kv word: 2*kt + half)
  const unsigned long long* mp0 = mbits + ((size_t)b * SLEN + (q0 + w * 32 + ql)) * 32;
  const unsigned long long* mp1 = mp0 + 16 * 32;

  // V-frag read base (byte) within a [64][64] half: chunk c via ^ (c<<5)
  int vbyte0 = (ql << 7) + (((g >> 1) ^ (ql & 7)) << 4) + ((g & 1) << 3);

  // Q fragments in registers (wave owns 32 q rows; Q pre-scaled by 0.125*L2E)
  bf16x8_t qf[2][2];
#pragma unroll
  for (int mi = 0; mi < 2; ++mi)
#pragma unroll
    for (int kk = 0; kk < 2; ++kk) {
      int row = q0 + w * 32 + mi * 16 + ql;
      qf[mi][kk] = *(const bf16x8_t*)(Qb + (size_t)row * 64 + kk * 32 + g * 8);
    }

  s16x4_t ones4 = {0x3F80, 0x3F80, 0x3F80, 0x3F80};  // 4x bf16 1.0

  f32x4_t aco[2][4] = {};     // O^T: dv=dvf*16+4g+r, q=mi*16+ql
  f32x4_t slacc[2] = {};      // l[q=ql] via ones-MFMA

  // ---- prologue: stage 128-kv tile 0 (both halves) ----
#pragma unroll
  for (int hh = 0; hh < 2; ++hh) {
    gload_lds16(kS0 + hh * 4096, (unsigned short*)lK[0][hh] + doff);
    gload_lds16(vS0 + hh * 64,   (unsigned short*)lV[0][hh] + doff);
  }
  kS0 += 8192; vS0 += 128;
  __syncthreads();

  int cur = 0;
  for (int kt = 0; kt < SLEN / 128; ++kt) {
    // ---- issue next 128-kv tile staging (hides under this tile's compute) ----
    if (kt + 1 < SLEN / 128) {
#pragma unroll
      for (int hh = 0; hh < 2; ++hh) {
        gload_lds16(kS0 + hh * 4096, (unsigned short*)lK[cur ^ 1][hh] + doff);
        gload_lds16(vS0 + hh * 64,   (unsigned short*)lV[cur ^ 1][hh] + doff);
      }
      kS0 += 8192; vS0 += 128;
    }

#pragma unroll
    for (int hh = 0; hh < 2; ++hh) {
      unsigned long long bg0 = mp0[2 * kt + hh] >> (4 * g);
      unsigned long long bg1 = mp1[2 * kt + hh] >> (4 * g);

      const unsigned short* kbuf = lK[cur][hh];
      const unsigned short* vbuf = lV[cur][hh];

      // ---- QK^T swapped: st[mi][ni][r] = S_log2[kv=ni*16+4g+r][q] ----
      f32x4_t st[2][4];
#pragma unroll
      for (int mi = 0; mi < 2; ++mi)
#pragma unroll
        for (int ni = 0; ni < 4; ++ni) st[mi][ni] = (f32x4_t){0.f, 0.f, 0.f, 0.f};
      __builtin_amdgcn_s_setprio(1);
#pragma unroll
      for (int kk = 0; kk < 2; ++kk) {
        bf16x8_t kf[4];
#pragma unroll
        for (int ni = 0; ni < 4; ++ni)
          kf[ni] = frag_ld(kbuf, ni * 16 + ql, kk * 4 + g);
#pragma unroll
        for (int mi = 0; mi < 2; ++mi)
#pragma unroll
          for (int ni = 0; ni < 4; ++ni)
            st[mi][ni] = __builtin_amdgcn_mfma_f32_16x16x32_bf16(kf[ni], qf[mi][kk],
                                                                 st[mi][ni], 0, 0, 0);
      }
      __builtin_amdgcn_s_setprio(0);

      // ---- static-max softmax: p = mask ? 2^st : 0, packed IN REGISTERS ----
      unsigned int pb[2][4][2];
#pragma unroll
      for (int mi = 0; mi < 2; ++mi) {
        unsigned long long bgs = mi ? bg1 : bg0;
        unsigned int mw0 = (unsigned int)bgs;          // ni 0,1 bits
        unsigned int mw1 = (unsigned int)(bgs >> 32);  // ni 2,3 bits
#pragma unroll
        for (int ni = 0; ni < 4; ++ni) {
          unsigned int mword = (ni < 2) ? mw0 : mw1;
          int base = (ni & 1) * 16;
          float p[4];
#pragma unroll
          for (int r = 0; r < 4; ++r) {
            float e = fast_exp2(st[mi][ni][r]);
            p[r] = ((mword >> (base + r)) & 1u) ? e : 0.f;
          }
          pb[mi][ni][0] = packbf(p[0], p[1]);
          pb[mi][ni][1] = packbf(p[2], p[3]);
        }
      }

      // ---- PV as O^T via 16x16x16 MFMA: P^T regs are the B-operand ----
      __builtin_amdgcn_s_setprio(1);
#pragma unroll
      for (int c = 0; c < 4; ++c) {
        s16x4_t vfa[4];
#pragma unroll
        for (int dvf = 0; dvf < 4; ++dvf) {
          union { uint2 u; s16x4_t s; } t;
          t.u = *(const uint2*)((const char*)vbuf + ((vbyte0 ^ (c << 5)) + dvf * 2048));
          vfa[dvf] = t.s;
        }
#pragma unroll
        for (int mi = 0; mi < 2; ++mi) {
          union { unsigned int u[2]; s16x4_t s; } pp;
          pp.u[0] = pb[mi][c][0]; pp.u[1] = pb[mi][c][1];
          slacc[mi] = mfma16x16(ones4, pp.s, slacc[mi]);
#pragma unroll
          for (int dvf = 0; dvf < 4; ++dvf)
            aco[mi][dvf] = mfma16x16(vfa[dvf], pp.s, aco[mi][dvf]);
        }
      }
      __builtin_amdgcn_s_setprio(0);
    }

    __syncthreads();  // drains vmcnt (K/V prefetch); releases buffers
    cur ^= 1;
  }

  // epilogue: normalize O^T, transpose through lK scratch (wave-private rows)
  unsigned short* eb = (unsigned short*)lK;  // need 256 rows x 128B = 32KB = lK
#pragma unroll
  for (int mi = 0; mi < 2; ++mi) {
    float inv = 1.0f / slacc[mi][0];
    int prow = w * 32 + mi * 16 + ql;        // 0..255
#pragma unroll
    for (int dvf = 0; dvf < 4; ++dvf) {
      unsigned int lo = packbf(aco[mi][dvf][0] * inv, aco[mi][dvf][1] * inv);
      unsigned int hi = packbf(aco[mi][dvf][2] * inv, aco[mi][dvf][3] * inv);
      int sl = (2 * dvf + (g >> 1)) ^ (prow & 7);
      *(uint2*)((char*)eb + prow * 128 + sl * 16 + (g & 1) * 8) = make_uint2(lo, hi);
    }
  }
#pragma unroll
  for (int it = 0; it < 8; ++it) {
    int rloc = g + 4 * it;
    int row = w * 32 + rloc;
    int sl = (ql >> 1) ^ (row & 7);
    uint2 v = *(const uint2*)((const char*)eb + row * 128 + sl * 16 + (ql & 1) * 8);
    int qrow = q0 + row;
    *(uint2*)(O + (((size_t)b * SLEN + qrow) << 10) + h * 64 + ql * 4) = v;
  }
}

// ---------------------------------------------------------------------------
extern "C" void kernel_launch(void* const* d_in, const int* in_sizes, int n_in,
                              void* d_out, int out_size, void* d_ws, size_t ws_size,
                              hipStream_t stream) {
  (void)in_sizes; (void)n_in; (void)out_size; (void)ws_size;
  const float* xq = (const float*)d_in[0];
  const float* xk = (const float*)d_in[1];
  const float* xv = (const float*)d_in[2];
  const void*  mask = d_in[3];
  const float* wq = (const float*)d_in[4];
  const float* bq = (const float*)d_in[5];
  const float* wk = (const float*)d_in[6];
  const float* bk = (const float*)d_in[7];
  const float* wv = (const float*)d_in[8];
  const float* bv = (const float*)d_in[9];
  const float* wo = (const float*)d_in[10];
  const float* bo = (const float*)d_in[11];
  float* out = (float*)d_out;

  char* ws = (char*)d_ws;
  unsigned short* Xq   = (unsigned short*)(ws);                   // 16 MiB, later Ob
  unsigned short* Ob   = (unsigned short*)(ws);                   // overlays Xq
  unsigned short* Wt   = (unsigned short*)(ws + 16777216ull);     // 8 MiB packed weights
  unsigned short* QKV  = (unsigned short*)(ws + 25165824ull);     // 48 MiB
  unsigned int*   flag = (unsigned int*)(ws + 75497472ull);       // 4 B
  // d_out overlay (32 MiB): qkv phase Xk [0,16M), Xv [16,32M);
  // afterwards bitmask [16M,18M). gemm_out overwrites at the end.
  unsigned short* Xk  = (unsigned short*)d_out;
  unsigned short* Xv  = (unsigned short*)((char*)d_out + 16777216ull);
  unsigned long long* mbits = (unsigned long long*)((char*)d_out + 16777216ull);

  detect_mask_kernel<<<1, 256, 0, stream>>>((const unsigned int*)mask, flag);
  pack_w_kernel<<<dim3(1024, 4), 256, 0, stream>>>(wq, wk, wv, wo, Wt);
  cvt_x_kernel<<<dim3(8192, 3), 256, 0, stream>>>(xq, xk, xv, Xq, Xk, Xv);
  gemm_qkv_kernel<<<dim3(64, 8, 3), 256, 0, stream>>>(Xq, Xk, Xv, Wt, bq, bk, bv, QKV);
  mask_bits_kernel<<<4096, 256, 0, stream>>>(mask, flag, mbits);   // Xv region now dead
  attn_kernel<<<512, 512, 0, stream>>>(QKV, QKV + 8388608ull,
                                       QKV + 16777216ull, mbits, Ob);  // Xq dead
  gemm_out_kernel<<<dim3(64, 8), 256, 0, stream>>>(Ob, Wt + 3ull * (HID * HID), bo, out);
}

// Round 19
// 289.539 us; speedup vs baseline: 1.0414x; 1.0008x over previous
//
#include <hip/hip_runtime.h>
#include <stdint.h>

// ---------------------------------------------------------------------------
// MHA: B=4 S=2048 H=16 Dk=Dv=64 HIDDEN=1024, fp32 in/out, bf16 MFMA compute.
// Pipeline: detect -> prep(FUSED cvt_x + pack_w + mask_bits) ->
//           gemm_qkv(MERGED z, BK=32, z=2 writes V^T) -> attn -> gemm_out
// Round 19: prep fusion. cvt_x (24576 blk) + pack_w (4096) + mask_bits (4096)
// are mutually independent -> one 32768-block launch (block-uniform branch,
// bodies unchanged). One BW ramp/tail instead of three; 2 fewer dispatches.
// attn = round-18 champion (QBLK=256/8 waves, KVBLK=128): 122.3us, 88% issue.
// Scratch ws (72 MiB + 4B):
//   [0,16MiB)   Xq (bf16) ... later reused as Ob (attn out)
//   [16,24MiB)  Wt  (packed bf16 weights, 4x 1024x1024, N-major)
//   [24,72MiB)  QKV (bf16): z=0 Q, z=1 K (std [bh][s][64]); z=2 VT [bh][dv][s]
//   @72MiB      mask-dtype flag (4B)
// d_out overlay (32 MiB): qkv phase: Xk [0,16), Xv [16,32); bitmask [16,18)
//   written by prep BEFORE Xv?  NO - bitmask lives at [16,18) which overlaps
//   Xv!  -> bitmask moved to ws @72MiB+4K?  No: bitmask is 2MiB. Resolution:
//   bitmask goes to d_out [16,18) AFTER Xv dies?  prep writes both.  =>
//   bitmask placed at d_out + 30MiB (Xv occupies [16,30.0)? Xv is 16MiB...
//   Final layout: Xk d_out[0,16), Xv d_out[16,32) are BOTH dead after
//   gemm_qkv; bitmask CANNOT overlap them while prep writes all three.
//   out_size = 8192x1024 fp32 = 32MiB exactly -> no spare room in d_out.
//   => bitmask lives in ws at 72MiB+64B (ws_size >= 72MiB+2MiB+64B holds:
//   prior rounds used 72MiB+4B of a larger buffer; keep bitmask in ws).
// ---------------------------------------------------------------------------

typedef __bf16 bf16x8_t __attribute__((ext_vector_type(8)));
typedef float f32x4_t __attribute__((ext_vector_type(4)));
typedef short s16x4_t __attribute__((ext_vector_type(4)));

#define HID   1024
#define SLEN  2048
#define BATCH 4
#define NH    16
#define MROWS 8192   // BATCH*SLEN
#define L2E   1.44269504f

__device__ __forceinline__ unsigned short bfbits(float f) {
  union { __bf16 h; unsigned short u; } v; v.h = (__bf16)f; return v.u;
}
__device__ __forceinline__ unsigned int packbf(float a, float b) {
  return (unsigned int)bfbits(a) | ((unsigned int)bfbits(b) << 16);
}
__device__ __forceinline__ float fast_exp2(float x) {
#if __has_builtin(__builtin_amdgcn_exp2f)
  return __builtin_amdgcn_exp2f(x);
#else
  return __exp2f(x);
#endif
}

__device__ __forceinline__ f32x4_t mfma16x16(s16x4_t a, s16x4_t b, f32x4_t c) {
#if __has_builtin(__builtin_amdgcn_mfma_f32_16x16x16bf16_1k)
  return __builtin_amdgcn_mfma_f32_16x16x16bf16_1k(a, b, c, 0, 0, 0);
#else
  asm("v_mfma_f32_16x16x16_bf16 %0, %1, %2, %0" : "+v"(c) : "v"(a), "v"(b));
  return c;
#endif
}

__device__ __forceinline__ void gload_lds16(const void* g, void* l) {
  __builtin_amdgcn_global_load_lds((const __attribute__((address_space(1))) void*)g,
                                   (__attribute__((address_space(3))) void*)l,
                                   16, 0, 0);
}

// 64-wide LDS rows (128B, 8 slots of 16B): physical slot = logical ^ (row & 7)
__device__ __forceinline__ bf16x8_t frag_ld(const unsigned short* lds, int row, int sblk) {
  int sp = sblk ^ (row & 7);
  return *(const bf16x8_t*)(lds + (row << 6) + (sp << 3));
}
// 32-wide LDS rows (64B, 4 slots of 16B): slot = logical ^ (row&3) ^ ((row>>2)&3)
__device__ __forceinline__ bf16x8_t frag_ld32(const unsigned short* lds, int row, int g) {
  int sp = g ^ (row & 3) ^ ((row >> 2) & 3);
  return *(const bf16x8_t*)(lds + (row << 5) + (sp << 3));
}

// ---- mask dtype detector: bool bytes (1B) vs int32 --------------------------
__global__ void detect_mask_kernel(const unsigned int* __restrict__ m,
                                   unsigned int* __restrict__ flag) {
  unsigned int v = m[threadIdx.x];
  unsigned long long b = __ballot(v > 1u);         // packed bools give words > 1
  if (threadIdx.x == 0) flag[0] = 0u;
  __syncthreads();
  if ((threadIdx.x & 63) == 0 && b) atomicOr(flag, 1u);  // 1 => byte mask
}

// ---- FUSED prep: cvt_x (blocks 0..24575) + pack_w (24576..28671)
//                  + mask_bits (28672..32767) ---------------------------------
__global__ __launch_bounds__(256) void prep_kernel(
    const float* __restrict__ xq, const float* __restrict__ xk,
    const float* __restrict__ xv, unsigned short* __restrict__ dq,
    unsigned short* __restrict__ dk, unsigned short* __restrict__ dv,
    const float* __restrict__ wq, const float* __restrict__ wk,
    const float* __restrict__ wv, const float* __restrict__ wo,
    unsigned short* __restrict__ wt, const void* __restrict__ maskp,
    const unsigned int* __restrict__ flag, unsigned long long* __restrict__ bits) {
  int bid = blockIdx.x;
  int tid = threadIdx.x;
  if (bid < 24576) {
    // ---- cvt_x ----
    int z = bid >> 13;
    int x = bid & 8191;
    const float* src = z == 0 ? xq : (z == 1 ? xk : xv);
    unsigned short* dst = z == 0 ? dq : (z == 1 ? dk : dv);
    size_t base = (size_t)x * 1024 + (size_t)tid * 4;
    float4 v = *(const float4*)(src + base);
    ushort4 o;
    o.x = bfbits(v.x); o.y = bfbits(v.y); o.z = bfbits(v.z); o.w = bfbits(v.w);
    *(ushort4*)(dst + base) = o;
  } else if (bid < 28672) {
    // ---- pack_w ----
    int id2 = bid - 24576;
    int z = id2 >> 10;
    int x = id2 & 1023;
    int id = x * 256 + tid;
    int n = id >> 8;
    int d0 = (id & 255) << 2;
    ushort4 o;
    if (z < 3) {
      const float* w = z == 0 ? wq : (z == 1 ? wk : wv);
      const float* base = w + (size_t)(n >> 6) * (HID * 64) + (n & 63);
      o.x = bfbits(base[(size_t)(d0 + 0) * 64]);
      o.y = bfbits(base[(size_t)(d0 + 1) * 64]);
      o.z = bfbits(base[(size_t)(d0 + 2) * 64]);
      o.w = bfbits(base[(size_t)(d0 + 3) * 64]);
    } else {
      o.x = bfbits(wo[(size_t)(d0 + 0) * HID + n]);
      o.y = bfbits(wo[(size_t)(d0 + 1) * HID + n]);
      o.z = bfbits(wo[(size_t)(d0 + 2) * HID + n]);
      o.w = bfbits(wo[(size_t)(d0 + 3) * HID + n]);
    }
    *(ushort4*)(wt + (size_t)z * (HID * HID) + (size_t)n * HID + d0) = o;
  } else {
    // ---- mask_bits ----
    int x = bid - 28672;
    int lane = tid & 63, wv2 = tid >> 6;
    bool bytemask = flag[0] != 0u;
    size_t w0 = (size_t)x * 64 + (size_t)wv2 * 16;
    for (int it = 0; it < 16; ++it) {
      size_t word = w0 + it;
      unsigned int v;
      if (bytemask) v = ((const unsigned char*)maskp)[word * 64 + lane];
      else          v = ((const unsigned int*)maskp)[word * 64 + lane];
      unsigned long long bm = __ballot(v != 0u);
      if (lane == 0) bits[word] = bm;
    }
  }
}

// ---- MERGED QKV GEMM: 128x128 tile, BK=32, dbuf LDS 32KB --------------------
__device__ __forceinline__ void gemm_stage32(const unsigned short* __restrict__ A,
    const unsigned short* __restrict__ B, unsigned short* la, unsigned short* lb,
    int tid, int w, int kt) {
#pragma unroll
  for (int i = 0; i < 2; ++i) {
    int flat = i * 256 + tid;
    int row = flat >> 2;
    int sl = (flat & 3) ^ (row & 3) ^ ((row >> 2) & 3);  // inverse-swz SOURCE
    gload_lds16(A + (size_t)row * HID + kt + sl * 8, la + ((i * 256 + w * 64) << 3));
    gload_lds16(B + (size_t)row * HID + kt + sl * 8, lb + ((i * 256 + w * 64) << 3));
  }
}

__global__ __launch_bounds__(256) void gemm_qkv_kernel(
    const unsigned short* __restrict__ Xq, const unsigned short* __restrict__ Xk,
    const unsigned short* __restrict__ Xv, const unsigned short* __restrict__ Wt,
    const float* __restrict__ bq, const float* __restrict__ bk,
    const float* __restrict__ bv, unsigned short* __restrict__ QKV) {
  __shared__ __align__(16) unsigned short lA[2][128 * 32];
  __shared__ __align__(16) unsigned short lB[2][128 * 32];
  int z = blockIdx.z;
  const unsigned short* Ain = z == 0 ? Xq : (z == 1 ? Xk : Xv);
  const float* bias = z == 0 ? bq : (z == 1 ? bk : bv);
  float scale = z == 0 ? 0.125f * L2E : 1.0f;
  int m0 = blockIdx.x * 128, n0 = blockIdx.y * 128;
  const unsigned short* A = Ain + (size_t)m0 * HID;
  const unsigned short* B = Wt + (size_t)z * (HID * HID) + (size_t)n0 * HID;
  unsigned short* Out = QKV + (size_t)z * ((size_t)MROWS * 1024);

  f32x4_t acc[4][4] = {};
  int tid = threadIdx.x, lane = tid & 63, w = tid >> 6;
  int wr = (w >> 1) << 6, wc = (w & 1) << 6;
  int ql = lane & 15, g = lane >> 4;

  gemm_stage32(A, B, lA[0], lB[0], tid, w, 0);
  __syncthreads();
  int cur = 0;
  for (int kt = 0; kt < HID; kt += 32) {
    if (kt + 32 < HID)
      gemm_stage32(A, B, lA[cur ^ 1], lB[cur ^ 1], tid, w, kt + 32);
    const unsigned short* la = lA[cur];
    const unsigned short* lb = lB[cur];
    bf16x8_t af[4], bfr[4];
#pragma unroll
    for (int mi = 0; mi < 4; ++mi)
      af[mi] = frag_ld32(la, wr + mi * 16 + ql, g);
#pragma unroll
    for (int ni = 0; ni < 4; ++ni)
      bfr[ni] = frag_ld32(lb, wc + ni * 16 + ql, g);
#pragma unroll
    for (int mi = 0; mi < 4; ++mi)
#pragma unroll
      for (int ni = 0; ni < 4; ++ni)
        acc[mi][ni] = __builtin_amdgcn_mfma_f32_16x16x32_bf16(af[mi], bfr[ni],
                                                              acc[mi][ni], 0, 0, 0);
    __syncthreads();
    cur ^= 1;
  }

  if (z < 2) {
#pragma unroll
    for (int mi = 0; mi < 4; ++mi)
#pragma unroll
      for (int ni = 0; ni < 4; ++ni) {
        int col = n0 + wc + ni * 16 + ql;
        float bb = bias[col];
        int h = col >> 6, d = col & 63;
#pragma unroll
        for (int r = 0; r < 4; ++r) {
          int row = m0 + wr + mi * 16 + (g << 2) + r;
          int b = row >> 11, s = row & 2047;
          Out[((((size_t)b * NH + h) * SLEN + s) << 6) + d] =
              bfbits((acc[mi][ni][r] + bb) * scale);
        }
      }
  } else {
    // V: transpose in wave-private 8KB LDS, store as VT[bh][dv][s]
    unsigned short* tb = (w < 2) ? lA[w] : lB[w - 2];
    unsigned int* tu = (unsigned int*)tb;
#pragma unroll
    for (int mi = 0; mi < 4; ++mi)
#pragma unroll
      for (int ni = 0; ni < 4; ++ni) {
        int col = n0 + wc + ni * 16 + ql;
        float bb = bias[col];
        int dl = ni * 16 + ql;
        int sp0 = 8 * mi + 2 * g;
        unsigned int v0 = packbf(acc[mi][ni][0] + bb, acc[mi][ni][1] + bb);
        unsigned int v1 = packbf(acc[mi][ni][2] + bb, acc[mi][ni][3] + bb);
        int slot = (sp0 >> 2) ^ (dl & 7);
        *(uint2*)(tu + dl * 32 + slot * 4 + (sp0 & 3)) = make_uint2(v0, v1);
      }
    int srow = m0 + wr;
    int b = srow >> 11, sl_ = srow & 2047;
    int h = (n0 + wc) >> 6;
    unsigned short* VTo = Out + (((size_t)(b * NH + h) * 64) * SLEN);
#pragma unroll
    for (int pass = 0; pass < 8; ++pass) {
      int dl = (lane >> 3) + 8 * pass;
      int slot = lane & 7;
      uint4 vv = *(const uint4*)(tu + dl * 32 + ((slot ^ (dl & 7)) << 2));
      *(uint4*)(VTo + (size_t)dl * SLEN + sl_ + slot * 8) = vv;
    }
  }
}

// ---- output projection GEMM: champion BK=64 2-phase -------------------------
__device__ __forceinline__ void gemm_stage(const unsigned short* __restrict__ A,
    const unsigned short* __restrict__ B, unsigned short* la, unsigned short* lb,
    int tid, int w, int kt) {
#pragma unroll
  for (int i = 0; i < 4; ++i) {
    int flat = i * 256 + tid;
    int row = flat >> 3;
    int sl = (flat & 7) ^ (row & 7);
    gload_lds16(A + (size_t)row * HID + kt + sl * 8, la + ((i * 256 + w * 64) << 3));
    gload_lds16(B + (size_t)row * HID + kt + sl * 8, lb + ((i * 256 + w * 64) << 3));
  }
}

__global__ __launch_bounds__(256) void gemm_out_kernel(
    const unsigned short* __restrict__ Ob, const unsigned short* __restrict__ WoT,
    const float* __restrict__ bo, float* __restrict__ out) {
  __shared__ __align__(16) unsigned short lA[2][128 * 64];
  __shared__ __align__(16) unsigned short lB[2][128 * 64];
  int m0 = blockIdx.x * 128, n0 = blockIdx.y * 128;
  const unsigned short* A = Ob + (size_t)m0 * HID;
  const unsigned short* B = WoT + (size_t)n0 * HID;
  f32x4_t acc[4][4] = {};
  int tid = threadIdx.x;
  int lane = tid & 63, w = tid >> 6;
  int wr = (w >> 1) << 6, wc = (w & 1) << 6;
  gemm_stage(A, B, lA[0], lB[0], tid, w, 0);
  __syncthreads();
  int cur = 0;
  for (int kt = 0; kt < HID; kt += 64) {
    if (kt + 64 < HID)
      gemm_stage(A, B, lA[cur ^ 1], lB[cur ^ 1], tid, w, kt + 64);
    const unsigned short* la = lA[cur];
    const unsigned short* lb = lB[cur];
#pragma unroll
    for (int kk = 0; kk < 2; ++kk) {
      bf16x8_t af[4], bfr[4];
#pragma unroll
      for (int mi = 0; mi < 4; ++mi)
        af[mi] = frag_ld(la, wr + mi * 16 + (lane & 15), kk * 4 + (lane >> 4));
#pragma unroll
      for (int ni = 0; ni < 4; ++ni)
        bfr[ni] = frag_ld(lb, wc + ni * 16 + (lane & 15), kk * 4 + (lane >> 4));
#pragma unroll
      for (int mi = 0; mi < 4; ++mi)
#pragma unroll
        for (int ni = 0; ni < 4; ++ni)
          acc[mi][ni] = __builtin_amdgcn_mfma_f32_16x16x32_bf16(af[mi], bfr[ni],
                                                                acc[mi][ni], 0, 0, 0);
    }
    __syncthreads();
    cur ^= 1;
  }
#pragma unroll
  for (int mi = 0; mi < 4; ++mi)
#pragma unroll
    for (int ni = 0; ni < 4; ++ni) {
      int col = n0 + wc + ni * 16 + (lane & 15);
      float bb = bo[col];
#pragma unroll
      for (int r = 0; r < 4; ++r) {
        int row = m0 + wr + mi * 16 + ((lane >> 4) << 2) + r;
        out[(size_t)row * HID + col] = acc[mi][ni][r] + bb;
      }
    }
}

// ---- flash attention: swapped QK^T, static-max softmax, register-P PV -------
// QBLK=256 (8 waves), KVBLK=128 (two 64-kv halves per barrier).
__global__ __launch_bounds__(512) void attn_kernel(
    const unsigned short* __restrict__ Q, const unsigned short* __restrict__ K,
    const unsigned short* __restrict__ VT, const unsigned long long* __restrict__ mbits,
    unsigned short* __restrict__ O) {
  __shared__ __align__(16) unsigned short lK[2][2][64 * 64];  // [buf][half][kv][d]
  __shared__ __align__(16) unsigned short lV[2][2][64 * 64];  // [buf][half][dv][kv]
  int tid = threadIdx.x, lane = tid & 63, w = tid >> 6;       // w in 0..7
  int g = lane >> 4, ql = lane & 15;
  int bid = blockIdx.x;                         // 512 blocks = 8 qt x 64 bh
  int bh = (bid & 7) * 8 + ((bid >> 3) >> 3);   // XCD-grouped, bijective
  int qt = (bid >> 3) & 7;
  int b = bh >> 4, h = bh & 15;
  int q0 = qt * 256;
  const unsigned short* Qb = Q + (size_t)bh * (SLEN * 64);

  // staging: 512 threads, 1 gload per K-half and V-half each (8KB per half)
  int r0 = tid >> 3;
  int s0 = (tid & 7) ^ (r0 & 7);
  const unsigned short* kS0 = K + (size_t)bh * (SLEN * 64) + (size_t)r0 * 64 + s0 * 8;
  const unsigned short* vS0 = VT + (size_t)bh * (64 * SLEN) + (size_t)r0 * SLEN + s0 * 8;
  int doff = tid << 3;
  const unsigned long long* mp0 = mbits + ((size_t)b * SLEN + (q0 + w * 32 + ql)) * 32;
  const unsigned long long* mp1 = mp0 + 16 * 32;

  int vbyte0 = (ql << 7) + (((g >> 1) ^ (ql & 7)) << 4) + ((g & 1) << 3);

  bf16x8_t qf[2][2];
#pragma unroll
  for (int mi = 0; mi < 2; ++mi)
#pragma unroll
    for (int kk = 0; kk < 2; ++kk) {
      int row = q0 + w * 32 + mi * 16 + ql;
      qf[mi][kk] = *(const bf16x8_t*)(Qb + (size_t)row * 64 + kk * 32 + g * 8);
    }

  s16x4_t ones4 = {0x3F80, 0x3F80, 0x3F80, 0x3F80};  // 4x bf16 1.0

  f32x4_t aco[2][4] = {};     // O^T: dv=dvf*16+4g+r, q=mi*16+ql
  f32x4_t slacc[2] = {};      // l[q=ql] via ones-MFMA

#pragma unroll
  for (int hh = 0; hh < 2; ++hh) {
    gload_lds16(kS0 + hh * 4096, (unsigned short*)lK[0][hh] + doff);
    gload_lds16(vS0 + hh * 64,   (unsigned short*)lV[0][hh] + doff);
  }
  kS0 += 8192; vS0 += 128;
  __syncthreads();

  int cur = 0;
  for (int kt = 0; kt < SLEN / 128; ++kt) {
    if (kt + 1 < SLEN / 128) {
#pragma unroll
      for (int hh = 0; hh < 2; ++hh) {
        gload_lds16(kS0 + hh * 4096, (unsigned short*)lK[cur ^ 1][hh] + doff);
        gload_lds16(vS0 + hh * 64,   (unsigned short*)lV[cur ^ 1][hh] + doff);
      }
      kS0 += 8192; vS0 += 128;
    }

#pragma unroll
    for (int hh = 0; hh < 2; ++hh) {
      unsigned long long bg0 = mp0[2 * kt + hh] >> (4 * g);
      unsigned long long bg1 = mp1[2 * kt + hh] >> (4 * g);

      const unsigned short* kbuf = lK[cur][hh];
      const unsigned short* vbuf = lV[cur][hh];

      f32x4_t st[2][4];
#pragma unroll
      for (int mi = 0; mi < 2; ++mi)
#pragma unroll
        for (int ni = 0; ni < 4; ++ni) st[mi][ni] = (f32x4_t){0.f, 0.f, 0.f, 0.f};
      __builtin_amdgcn_s_setprio(1);
#pragma unroll
      for (int kk = 0; kk < 2; ++kk) {
        bf16x8_t kf[4];
#pragma unroll
        for (int ni = 0; ni < 4; ++ni)
          kf[ni] = frag_ld(kbuf, ni * 16 + ql, kk * 4 + g);
#pragma unroll
        for (int mi = 0; mi < 2; ++mi)
#pragma unroll
          for (int ni = 0; ni < 4; ++ni)
            st[mi][ni] = __builtin_amdgcn_mfma_f32_16x16x32_bf16(kf[ni], qf[mi][kk],
                                                                 st[mi][ni], 0, 0, 0);
      }
      __builtin_amdgcn_s_setprio(0);

      unsigned int pb[2][4][2];
#pragma unroll
      for (int mi = 0; mi < 2; ++mi) {
        unsigned long long bgs = mi ? bg1 : bg0;
        unsigned int mw0 = (unsigned int)bgs;
        unsigned int mw1 = (unsigned int)(bgs >> 32);
#pragma unroll
        for (int ni = 0; ni < 4; ++ni) {
          unsigned int mword = (ni < 2) ? mw0 : mw1;
          int base = (ni & 1) * 16;
          float p[4];
#pragma unroll
          for (int r = 0; r < 4; ++r) {
            float e = fast_exp2(st[mi][ni][r]);
            p[r] = ((mword >> (base + r)) & 1u) ? e : 0.f;
          }
          pb[mi][ni][0] = packbf(p[0], p[1]);
          pb[mi][ni][1] = packbf(p[2], p[3]);
        }
      }

      __builtin_amdgcn_s_setprio(1);
#pragma unroll
      for (int c = 0; c < 4; ++c) {
        s16x4_t vfa[4];
#pragma unroll
        for (int dvf = 0; dvf < 4; ++dvf) {
          union { uint2 u; s16x4_t s; } t;
          t.u = *(const uint2*)((const char*)vbuf + ((vbyte0 ^ (c << 5)) + dvf * 2048));
          vfa[dvf] = t.s;
        }
#pragma unroll
        for (int mi = 0; mi < 2; ++mi) {
          union { unsigned int u[2]; s16x4_t s; } pp;
          pp.u[0] = pb[mi][c][0]; pp.u[1] = pb[mi][c][1];
          slacc[mi] = mfma16x16(ones4, pp.s, slacc[mi]);
#pragma unroll
          for (int dvf = 0; dvf < 4; ++dvf)
            aco[mi][dvf] = mfma16x16(vfa[dvf], pp.s, aco[mi][dvf]);
        }
      }
      __builtin_amdgcn_s_setprio(0);
    }

    __syncthreads();
    cur ^= 1;
  }

  // epilogue: normalize O^T, transpose through lK scratch (wave-private rows)
  unsigned short* eb = (unsigned short*)lK;  // 256 rows x 128B = 32KB = lK
#pragma unroll
  for (int mi = 0; mi < 2; ++mi) {
    float inv = 1.0f / slacc[mi][0];
    int prow = w * 32 + mi * 16 + ql;        // 0..255
#pragma unroll
    for (int dvf = 0; dvf < 4; ++dvf) {
      unsigned int lo = packbf(aco[mi][dvf][0] * inv, aco[mi][dvf][1] * inv);
      unsigned int hi = packbf(aco[mi][dvf][2] * inv, aco[mi][dvf][3] * inv);
      int sl = (2 * dvf + (g >> 1)) ^ (prow & 7);
      *(uint2*)((char*)eb + prow * 128 + sl * 16 + (g & 1) * 8) = make_uint2(lo, hi);
    }
  }
#pragma unroll
  for (int it = 0; it < 8; ++it) {
    int rloc = g + 4 * it;
    int row = w * 32 + rloc;
    int sl = (ql >> 1) ^ (row & 7);
    uint2 v = *(const uint2*)((const char*)eb + row * 128 + sl * 16 + (ql & 1) * 8);
    int qrow = q0 + row;
    *(uint2*)(O + (((size_t)b * SLEN + qrow) << 10) + h * 64 + ql * 4) = v;
  }
}

// ---------------------------------------------------------------------------
extern "C" void kernel_launch(void* const* d_in, const int* in_sizes, int n_in,
                              void* d_out, int out_size, void* d_ws, size_t ws_size,
                              hipStream_t stream) {
  (void)in_sizes; (void)n_in; (void)out_size; (void)ws_size;
  const float* xq = (const float*)d_in[0];
  const float* xk = (const float*)d_in[1];
  const float* xv = (const float*)d_in[2];
  const void*  mask = d_in[3];
  const float* wq = (const float*)d_in[4];
  const float* bq = (const float*)d_in[5];
  const float* wk = (const float*)d_in[6];
  const float* bk = (const float*)d_in[7];
  const float* wv = (const float*)d_in[8];
  const float* bv = (const float*)d_in[9];
  const float* wo = (const float*)d_in[10];
  const float* bo = (const float*)d_in[11];
  float* out = (float*)d_out;

  char* ws = (char*)d_ws;
  unsigned short* Xq   = (unsigned short*)(ws);                   // 16 MiB, later Ob
  unsigned short* Ob   = (unsigned short*)(ws);                   // overlays Xq
  unsigned short* Wt   = (unsigned short*)(ws + 16777216ull);     // 8 MiB packed weights
  unsigned short* QKV  = (unsigned short*)(ws + 25165824ull);     // 48 MiB
  unsigned int*   flag = (unsigned int*)(ws + 75497472ull);       // 4 B
  // bitmask (2 MiB) in ws after flag (prep writes Xv concurrently, so it
  // can no longer share d_out[16,18) with Xv). 72MiB+64B .. 74MiB+64B.
  unsigned long long* mbits = (unsigned long long*)(ws + 75497536ull);
  // d_out overlay (32 MiB): qkv phase Xk [0,16M), Xv [16,32M); gemm_out
  // overwrites at the end.
  unsigned short* Xk  = (unsigned short*)d_out;
  unsigned short* Xv  = (unsigned short*)((char*)d_out + 16777216ull);

  detect_mask_kernel<<<1, 256, 0, stream>>>((const unsigned int*)mask, flag);
  prep_kernel<<<32768, 256, 0, stream>>>(xq, xk, xv, Xq, Xk, Xv,
                                         wq, wk, wv, wo, Wt, mask, flag, mbits);
  gemm_qkv_kernel<<<dim3(64, 8, 3), 256, 0, stream>>>(Xq, Xk, Xv, Wt, bq, bk, bv, QKV);
  attn_kernel<<<512, 512, 0, stream>>>(QKV, QKV + 8388608ull,
                                       QKV + 16777216ull, mbits, Ob);
  gemm_out_kernel<<<dim3(64, 8), 256, 0, stream>>>(Ob, Wt + 3ull * (HID * HID), bo, out);
}

// Round 20
// 288.224 us; speedup vs baseline: 1.0462x; 1.0046x over previous
//
#include <hip/hip_runtime.h>
#include <stdint.h>

// ---------------------------------------------------------------------------
// MHA: B=4 S=2048 H=16 Dk=Dv=64 HIDDEN=1024, fp32 in/out, bf16 MFMA compute.
// Pipeline: prep(FUSED cvt_x + pack_w + self-detecting mask_bits) ->
//           gemm_qkv(MERGED z, BK=32, z=2 writes V^T) -> attn -> gemm_out
// Round 20: detect_mask_kernel DELETED (mask dtype self-detected per wave in
// the mask_bits branch: wave-local ballot over first 64 words; P(false
// negative for bool mask) = 2^-192). One fewer dispatch, no flag dependency.
// All compute kernels byte-identical to round-19 champion (289.5us):
//   attn: QBLK=256 (8 waves), KVBLK=128 (2 halves/barrier) - 122us, 87% issue
//   gemm_qkv: merged z, 128x128/BK=32 - at 2-phase template ceiling (~690TF)
//   gemm_out: 128x128/BK=64 2-phase
// Session ledger: 487->289.5us. Reverted: r8 attn-32x32(+7), r9 512thr-gemm
// (+6), r10 K32-PV-lP(+7), r12 fused-cvt(+19). Wins: bitmask+swapped-QKT
// (-110), static-max softmax(-51), 2-phase pipe(-17), reg-P PV(-8), VT+hoist
// (-20), KVBLK128(-10), QBLK256(-5), merges(-6).
// Scratch ws (74 MiB): [0,16M) Xq/Ob | [16,24M) Wt | [24,72M) QKV
//   (z=0 Q, z=1 K std; z=2 VT[bh][dv][s]) | @72M+64B bitmask (2 MiB)
// d_out overlay (32 MiB): qkv phase Xk [0,16M), Xv [16,32M); gemm_out last.
// ---------------------------------------------------------------------------

typedef __bf16 bf16x8_t __attribute__((ext_vector_type(8)));
typedef float f32x4_t __attribute__((ext_vector_type(4)));
typedef short s16x4_t __attribute__((ext_vector_type(4)));

#define HID   1024
#define SLEN  2048
#define BATCH 4
#define NH    16
#define MROWS 8192   // BATCH*SLEN
#define L2E   1.44269504f

__device__ __forceinline__ unsigned short bfbits(float f) {
  union { __bf16 h; unsigned short u; } v; v.h = (__bf16)f; return v.u;
}
__device__ __forceinline__ unsigned int packbf(float a, float b) {
  return (unsigned int)bfbits(a) | ((unsigned int)bfbits(b) << 16);
}
__device__ __forceinline__ float fast_exp2(float x) {
#if __has_builtin(__builtin_amdgcn_exp2f)
  return __builtin_amdgcn_exp2f(x);
#else
  return __exp2f(x);
#endif
}

__device__ __forceinline__ f32x4_t mfma16x16(s16x4_t a, s16x4_t b, f32x4_t c) {
#if __has_builtin(__builtin_amdgcn_mfma_f32_16x16x16bf16_1k)
  return __builtin_amdgcn_mfma_f32_16x16x16bf16_1k(a, b, c, 0, 0, 0);
#else
  asm("v_mfma_f32_16x16x16_bf16 %0, %1, %2, %0" : "+v"(c) : "v"(a), "v"(b));
  return c;
#endif
}

__device__ __forceinline__ void gload_lds16(const void* g, void* l) {
  __builtin_amdgcn_global_load_lds((const __attribute__((address_space(1))) void*)g,
                                   (__attribute__((address_space(3))) void*)l,
                                   16, 0, 0);
}

// 64-wide LDS rows (128B, 8 slots of 16B): physical slot = logical ^ (row & 7)
__device__ __forceinline__ bf16x8_t frag_ld(const unsigned short* lds, int row, int sblk) {
  int sp = sblk ^ (row & 7);
  return *(const bf16x8_t*)(lds + (row << 6) + (sp << 3));
}
// 32-wide LDS rows (64B, 4 slots of 16B): slot = logical ^ (row&3) ^ ((row>>2)&3)
__device__ __forceinline__ bf16x8_t frag_ld32(const unsigned short* lds, int row, int g) {
  int sp = g ^ (row & 3) ^ ((row >> 2) & 3);
  return *(const bf16x8_t*)(lds + (row << 5) + (sp << 3));
}

// ---- FUSED prep: cvt_x (blocks 0..24575) + pack_w (24576..28671)
//                  + mask_bits w/ in-wave dtype detect (28672..32767) ---------
__global__ __launch_bounds__(256) void prep_kernel(
    const float* __restrict__ xq, const float* __restrict__ xk,
    const float* __restrict__ xv, unsigned short* __restrict__ dq,
    unsigned short* __restrict__ dk, unsigned short* __restrict__ dv,
    const float* __restrict__ wq, const float* __restrict__ wk,
    const float* __restrict__ wv, const float* __restrict__ wo,
    unsigned short* __restrict__ wt, const void* __restrict__ maskp,
    unsigned long long* __restrict__ bits) {
  int bid = blockIdx.x;
  int tid = threadIdx.x;
  if (bid < 24576) {
    // ---- cvt_x ----
    int z = bid >> 13;
    int x = bid & 8191;
    const float* src = z == 0 ? xq : (z == 1 ? xk : xv);
    unsigned short* dst = z == 0 ? dq : (z == 1 ? dk : dv);
    size_t base = (size_t)x * 1024 + (size_t)tid * 4;
    float4 v = *(const float4*)(src + base);
    ushort4 o;
    o.x = bfbits(v.x); o.y = bfbits(v.y); o.z = bfbits(v.z); o.w = bfbits(v.w);
    *(ushort4*)(dst + base) = o;
  } else if (bid < 28672) {
    // ---- pack_w ----
    int id2 = bid - 24576;
    int z = id2 >> 10;
    int x = id2 & 1023;
    int id = x * 256 + tid;
    int n = id >> 8;
    int d0 = (id & 255) << 2;
    ushort4 o;
    if (z < 3) {
      const float* w = z == 0 ? wq : (z == 1 ? wk : wv);
      const float* base = w + (size_t)(n >> 6) * (HID * 64) + (n & 63);
      o.x = bfbits(base[(size_t)(d0 + 0) * 64]);
      o.y = bfbits(base[(size_t)(d0 + 1) * 64]);
      o.z = bfbits(base[(size_t)(d0 + 2) * 64]);
      o.w = bfbits(base[(size_t)(d0 + 3) * 64]);
    } else {
      o.x = bfbits(wo[(size_t)(d0 + 0) * HID + n]);
      o.y = bfbits(wo[(size_t)(d0 + 1) * HID + n]);
      o.z = bfbits(wo[(size_t)(d0 + 2) * HID + n]);
      o.w = bfbits(wo[(size_t)(d0 + 3) * HID + n]);
    }
    *(ushort4*)(wt + (size_t)z * (HID * HID) + (size_t)n * HID + d0) = o;
  } else {
    // ---- mask_bits with in-wave dtype detection ----
    // Every wave reads words [0,64): packed bools give words >1 w.p. 1-2^-192.
    int x = bid - 28672;
    int lane = tid & 63, wv2 = tid >> 6;
    unsigned int dvw = ((const unsigned int*)maskp)[lane];
    bool bytemask = (__ballot(dvw > 1u) != 0ull);
    size_t w0 = (size_t)x * 64 + (size_t)wv2 * 16;
    for (int it = 0; it < 16; ++it) {
      size_t word = w0 + it;
      unsigned int v;
      if (bytemask) v = ((const unsigned char*)maskp)[word * 64 + lane];
      else          v = ((const unsigned int*)maskp)[word * 64 + lane];
      unsigned long long bm = __ballot(v != 0u);
      if (lane == 0) bits[word] = bm;
    }
  }
}

// ---- MERGED QKV GEMM: 128x128 tile, BK=32, dbuf LDS 32KB --------------------
__device__ __forceinline__ void gemm_stage32(const unsigned short* __restrict__ A,
    const unsigned short* __restrict__ B, unsigned short* la, unsigned short* lb,
    int tid, int w, int kt) {
#pragma unroll
  for (int i = 0; i < 2; ++i) {
    int flat = i * 256 + tid;
    int row = flat >> 2;
    int sl = (flat & 3) ^ (row & 3) ^ ((row >> 2) & 3);  // inverse-swz SOURCE
    gload_lds16(A + (size_t)row * HID + kt + sl * 8, la + ((i * 256 + w * 64) << 3));
    gload_lds16(B + (size_t)row * HID + kt + sl * 8, lb + ((i * 256 + w * 64) << 3));
  }
}

__global__ __launch_bounds__(256) void gemm_qkv_kernel(
    const unsigned short* __restrict__ Xq, const unsigned short* __restrict__ Xk,
    const unsigned short* __restrict__ Xv, const unsigned short* __restrict__ Wt,
    const float* __restrict__ bq, const float* __restrict__ bk,
    const float* __restrict__ bv, unsigned short* __restrict__ QKV) {
  __shared__ __align__(16) unsigned short lA[2][128 * 32];
  __shared__ __align__(16) unsigned short lB[2][128 * 32];
  int z = blockIdx.z;
  const unsigned short* Ain = z == 0 ? Xq : (z == 1 ? Xk : Xv);
  const float* bias = z == 0 ? bq : (z == 1 ? bk : bv);
  float scale = z == 0 ? 0.125f * L2E : 1.0f;
  int m0 = blockIdx.x * 128, n0 = blockIdx.y * 128;
  const unsigned short* A = Ain + (size_t)m0 * HID;
  const unsigned short* B = Wt + (size_t)z * (HID * HID) + (size_t)n0 * HID;
  unsigned short* Out = QKV + (size_t)z * ((size_t)MROWS * 1024);

  f32x4_t acc[4][4] = {};
  int tid = threadIdx.x, lane = tid & 63, w = tid >> 6;
  int wr = (w >> 1) << 6, wc = (w & 1) << 6;
  int ql = lane & 15, g = lane >> 4;

  gemm_stage32(A, B, lA[0], lB[0], tid, w, 0);
  __syncthreads();
  int cur = 0;
  for (int kt = 0; kt < HID; kt += 32) {
    if (kt + 32 < HID)
      gemm_stage32(A, B, lA[cur ^ 1], lB[cur ^ 1], tid, w, kt + 32);
    const unsigned short* la = lA[cur];
    const unsigned short* lb = lB[cur];
    bf16x8_t af[4], bfr[4];
#pragma unroll
    for (int mi = 0; mi < 4; ++mi)
      af[mi] = frag_ld32(la, wr + mi * 16 + ql, g);
#pragma unroll
    for (int ni = 0; ni < 4; ++ni)
      bfr[ni] = frag_ld32(lb, wc + ni * 16 + ql, g);
#pragma unroll
    for (int mi = 0; mi < 4; ++mi)
#pragma unroll
      for (int ni = 0; ni < 4; ++ni)
        acc[mi][ni] = __builtin_amdgcn_mfma_f32_16x16x32_bf16(af[mi], bfr[ni],
                                                              acc[mi][ni], 0, 0, 0);
    __syncthreads();
    cur ^= 1;
  }

  if (z < 2) {
#pragma unroll
    for (int mi = 0; mi < 4; ++mi)
#pragma unroll
      for (int ni = 0; ni < 4; ++ni) {
        int col = n0 + wc + ni * 16 + ql;
        float bb = bias[col];
        int h = col >> 6, d = col & 63;
#pragma unroll
        for (int r = 0; r < 4; ++r) {
          int row = m0 + wr + mi * 16 + (g << 2) + r;
          int b = row >> 11, s = row & 2047;
          Out[((((size_t)b * NH + h) * SLEN + s) << 6) + d] =
              bfbits((acc[mi][ni][r] + bb) * scale);
        }
      }
  } else {
    // V: transpose in wave-private 8KB LDS, store as VT[bh][dv][s]
    unsigned short* tb = (w < 2) ? lA[w] : lB[w - 2];
    unsigned int* tu = (unsigned int*)tb;
#pragma unroll
    for (int mi = 0; mi < 4; ++mi)
#pragma unroll
      for (int ni = 0; ni < 4; ++ni) {
        int col = n0 + wc + ni * 16 + ql;
        float bb = bias[col];
        int dl = ni * 16 + ql;
        int sp0 = 8 * mi + 2 * g;
        unsigned int v0 = packbf(acc[mi][ni][0] + bb, acc[mi][ni][1] + bb);
        unsigned int v1 = packbf(acc[mi][ni][2] + bb, acc[mi][ni][3] + bb);
        int slot = (sp0 >> 2) ^ (dl & 7);
        *(uint2*)(tu + dl * 32 + slot * 4 + (sp0 & 3)) = make_uint2(v0, v1);
      }
    int srow = m0 + wr;
    int b = srow >> 11, sl_ = srow & 2047;
    int h = (n0 + wc) >> 6;
    unsigned short* VTo = Out + (((size_t)(b * NH + h) * 64) * SLEN);
#pragma unroll
    for (int pass = 0; pass < 8; ++pass) {
      int dl = (lane >> 3) + 8 * pass;
      int slot = lane & 7;
      uint4 vv = *(const uint4*)(tu + dl * 32 + ((slot ^ (dl & 7)) << 2));
      *(uint4*)(VTo + (size_t)dl * SLEN + sl_ + slot * 8) = vv;
    }
  }
}

// ---- output projection GEMM: champion BK=64 2-phase -------------------------
__device__ __forceinline__ void gemm_stage(const unsigned short* __restrict__ A,
    const unsigned short* __restrict__ B, unsigned short* la, unsigned short* lb,
    int tid, int w, int kt) {
#pragma unroll
  for (int i = 0; i < 4; ++i) {
    int flat = i * 256 + tid;
    int row = flat >> 3;
    int sl = (flat & 7) ^ (row & 7);
    gload_lds16(A + (size_t)row * HID + kt + sl * 8, la + ((i * 256 + w * 64) << 3));
    gload_lds16(B + (size_t)row * HID + kt + sl * 8, lb + ((i * 256 + w * 64) << 3));
  }
}

__global__ __launch_bounds__(256) void gemm_out_kernel(
    const unsigned short* __restrict__ Ob, const unsigned short* __restrict__ WoT,
    const float* __restrict__ bo, float* __restrict__ out) {
  __shared__ __align__(16) unsigned short lA[2][128 * 64];
  __shared__ __align__(16) unsigned short lB[2][128 * 64];
  int m0 = blockIdx.x * 128, n0 = blockIdx.y * 128;
  const unsigned short* A = Ob + (size_t)m0 * HID;
  const unsigned short* B = WoT + (size_t)n0 * HID;
  f32x4_t acc[4][4] = {};
  int tid = threadIdx.x;
  int lane = tid & 63, w = tid >> 6;
  int wr = (w >> 1) << 6, wc = (w & 1) << 6;
  gemm_stage(A, B, lA[0], lB[0], tid, w, 0);
  __syncthreads();
  int cur = 0;
  for (int kt = 0; kt < HID; kt += 64) {
    if (kt + 64 < HID)
      gemm_stage(A, B, lA[cur ^ 1], lB[cur ^ 1], tid, w, kt + 64);
    const unsigned short* la = lA[cur];
    const unsigned short* lb = lB[cur];
#pragma unroll
    for (int kk = 0; kk < 2; ++kk) {
      bf16x8_t af[4], bfr[4];
#pragma unroll
      for (int mi = 0; mi < 4; ++mi)
        af[mi] = frag_ld(la, wr + mi * 16 + (lane & 15), kk * 4 + (lane >> 4));
#pragma unroll
      for (int ni = 0; ni < 4; ++ni)
        bfr[ni] = frag_ld(lb, wc + ni * 16 + (lane & 15), kk * 4 + (lane >> 4));
#pragma unroll
      for (int mi = 0; mi < 4; ++mi)
#pragma unroll
        for (int ni = 0; ni < 4; ++ni)
          acc[mi][ni] = __builtin_amdgcn_mfma_f32_16x16x32_bf16(af[mi], bfr[ni],
                                                                acc[mi][ni], 0, 0, 0);
    }
    __syncthreads();
    cur ^= 1;
  }
#pragma unroll
  for (int mi = 0; mi < 4; ++mi)
#pragma unroll
    for (int ni = 0; ni < 4; ++ni) {
      int col = n0 + wc + ni * 16 + (lane & 15);
      float bb = bo[col];
#pragma unroll
      for (int r = 0; r < 4; ++r) {
        int row = m0 + wr + mi * 16 + ((lane >> 4) << 2) + r;
        out[(size_t)row * HID + col] = acc[mi][ni][r] + bb;
      }
    }
}

// ---- flash attention: swapped QK^T, static-max softmax, register-P PV -------
// QBLK=256 (8 waves), KVBLK=128 (two 64-kv halves per barrier).
__global__ __launch_bounds__(512) void attn_kernel(
    const unsigned short* __restrict__ Q, const unsigned short* __restrict__ K,
    const unsigned short* __restrict__ VT, const unsigned long long* __restrict__ mbits,
    unsigned short* __restrict__ O) {
  __shared__ __align__(16) unsigned short lK[2][2][64 * 64];  // [buf][half][kv][d]
  __shared__ __align__(16) unsigned short lV[2][2][64 * 64];  // [buf][half][dv][kv]
  int tid = threadIdx.x, lane = tid & 63, w = tid >> 6;       // w in 0..7
  int g = lane >> 4, ql = lane & 15;
  int bid = blockIdx.x;                         // 512 blocks = 8 qt x 64 bh
  int bh = (bid & 7) * 8 + ((bid >> 3) >> 3);   // XCD-grouped, bijective
  int qt = (bid >> 3) & 7;
  int b = bh >> 4, h = bh & 15;
  int q0 = qt * 256;
  const unsigned short* Qb = Q + (size_t)bh * (SLEN * 64);

  // staging: 512 threads, 1 gload per K-half and V-half each (8KB per half)
  int r0 = tid >> 3;
  int s0 = (tid & 7) ^ (r0 & 7);
  const unsigned short* kS0 = K + (size_t)bh * (SLEN * 64) + (size_t)r0 * 64 + s0 * 8;
  const unsigned short* vS0 = VT + (size_t)bh * (64 * SLEN) + (size_t)r0 * SLEN + s0 * 8;
  int doff = tid << 3;
  const unsigned long long* mp0 = mbits + ((size_t)b * SLEN + (q0 + w * 32 + ql)) * 32;
  const unsigned long long* mp1 = mp0 + 16 * 32;

  int vbyte0 = (ql << 7) + (((g >> 1) ^ (ql & 7)) << 4) + ((g & 1) << 3);

  bf16x8_t qf[2][2];
#pragma unroll
  for (int mi = 0; mi < 2; ++mi)
#pragma unroll
    for (int kk = 0; kk < 2; ++kk) {
      int row = q0 + w * 32 + mi * 16 + ql;
      qf[mi][kk] = *(const bf16x8_t*)(Qb + (size_t)row * 64 + kk * 32 + g * 8);
    }

  s16x4_t ones4 = {0x3F80, 0x3F80, 0x3F80, 0x3F80};  // 4x bf16 1.0

  f32x4_t aco[2][4] = {};     // O^T: dv=dvf*16+4g+r, q=mi*16+ql
  f32x4_t slacc[2] = {};      // l[q=ql] via ones-MFMA

#pragma unroll
  for (int hh = 0; hh < 2; ++hh) {
    gload_lds16(kS0 + hh * 4096, (unsigned short*)lK[0][hh] + doff);
    gload_lds16(vS0 + hh * 64,   (unsigned short*)lV[0][hh] + doff);
  }
  kS0 += 8192; vS0 += 128;
  __syncthreads();

  int cur = 0;
  for (int kt = 0; kt < SLEN / 128; ++kt) {
    if (kt + 1 < SLEN / 128) {
#pragma unroll
      for (int hh = 0; hh < 2; ++hh) {
        gload_lds16(kS0 + hh * 4096, (unsigned short*)lK[cur ^ 1][hh] + doff);
        gload_lds16(vS0 + hh * 64,   (unsigned short*)lV[cur ^ 1][hh] + doff);
      }
      kS0 += 8192; vS0 += 128;
    }

#pragma unroll
    for (int hh = 0; hh < 2; ++hh) {
      unsigned long long bg0 = mp0[2 * kt + hh] >> (4 * g);
      unsigned long long bg1 = mp1[2 * kt + hh] >> (4 * g);

      const unsigned short* kbuf = lK[cur][hh];
      const unsigned short* vbuf = lV[cur][hh];

      f32x4_t st[2][4];
#pragma unroll
      for (int mi = 0; mi < 2; ++mi)
#pragma unroll
        for (int ni = 0; ni < 4; ++ni) st[mi][ni] = (f32x4_t){0.f, 0.f, 0.f, 0.f};
      __builtin_amdgcn_s_setprio(1);
#pragma unroll
      for (int kk = 0; kk < 2; ++kk) {
        bf16x8_t kf[4];
#pragma unroll
        for (int ni = 0; ni < 4; ++ni)
          kf[ni] = frag_ld(kbuf, ni * 16 + ql, kk * 4 + g);
#pragma unroll
        for (int mi = 0; mi < 2; ++mi)
#pragma unroll
          for (int ni = 0; ni < 4; ++ni)
            st[mi][ni] = __builtin_amdgcn_mfma_f32_16x16x32_bf16(kf[ni], qf[mi][kk],
                                                                 st[mi][ni], 0, 0, 0);
      }
      __builtin_amdgcn_s_setprio(0);

      unsigned int pb[2][4][2];
#pragma unroll
      for (int mi = 0; mi < 2; ++mi) {
        unsigned long long bgs = mi ? bg1 : bg0;
        unsigned int mw0 = (unsigned int)bgs;
        unsigned int mw1 = (unsigned int)(bgs >> 32);
#pragma unroll
        for (int ni = 0; ni < 4; ++ni) {
          unsigned int mword = (ni < 2) ? mw0 : mw1;
          int base = (ni & 1) * 16;
          float p[4];
#pragma unroll
          for (int r = 0; r < 4; ++r) {
            float e = fast_exp2(st[mi][ni][r]);
            p[r] = ((mword >> (base + r)) & 1u) ? e : 0.f;
          }
          pb[mi][ni][0] = packbf(p[0], p[1]);
          pb[mi][ni][1] = packbf(p[2], p[3]);
        }
      }

      __builtin_amdgcn_s_setprio(1);
#pragma unroll
      for (int c = 0; c < 4; ++c) {
        s16x4_t vfa[4];
#pragma unroll
        for (int dvf = 0; dvf < 4; ++dvf) {
          union { uint2 u; s16x4_t s; } t;
          t.u = *(const uint2*)((const char*)vbuf + ((vbyte0 ^ (c << 5)) + dvf * 2048));
          vfa[dvf] = t.s;
        }
#pragma unroll
        for (int mi = 0; mi < 2; ++mi) {
          union { unsigned int u[2]; s16x4_t s; } pp;
          pp.u[0] = pb[mi][c][0]; pp.u[1] = pb[mi][c][1];
          slacc[mi] = mfma16x16(ones4, pp.s, slacc[mi]);
#pragma unroll
          for (int dvf = 0; dvf < 4; ++dvf)
            aco[mi][dvf] = mfma16x16(vfa[dvf], pp.s, aco[mi][dvf]);
        }
      }
      __builtin_amdgcn_s_setprio(0);
    }

    __syncthreads();
    cur ^= 1;
  }

  // epilogue: normalize O^T, transpose through lK scratch (wave-private rows)
  unsigned short* eb = (unsigned short*)lK;  // 256 rows x 128B = 32KB = lK
#pragma unroll
  for (int mi = 0; mi < 2; ++mi) {
    float inv = 1.0f / slacc[mi][0];
    int prow = w * 32 + mi * 16 + ql;        // 0..255
#pragma unroll
    for (int dvf = 0; dvf < 4; ++dvf) {
      unsigned int lo = packbf(aco[mi][dvf][0] * inv, aco[mi][dvf][1] * inv);
      unsigned int hi = packbf(aco[mi][dvf][2] * inv, aco[mi][dvf][3] * inv);
      int sl = (2 * dvf + (g >> 1)) ^ (prow & 7);
      *(uint2*)((char*)eb + prow * 128 + sl * 16 + (g & 1) * 8) = make_uint2(lo, hi);
    }
  }
#pragma unroll
  for (int it = 0; it < 8; ++it) {
    int rloc = g + 4 * it;
    int row = w * 32 + rloc;
    int sl = (ql >> 1) ^ (row & 7);
    uint2 v = *(const uint2*)((const char*)eb + row * 128 + sl * 16 + (ql & 1) * 8);
    int qrow = q0 + row;
    *(uint2*)(O + (((size_t)b * SLEN + qrow) << 10) + h * 64 + ql * 4) = v;
  }
}

// ---------------------------------------------------------------------------
extern "C" void kernel_launch(void* const* d_in, const int* in_sizes, int n_in,
                              void* d_out, int out_size, void* d_ws, size_t ws_size,
                              hipStream_t stream) {
  (void)in_sizes; (void)n_in; (void)out_size; (void)ws_size;
  const float* xq = (const float*)d_in[0];
  const float* xk = (const float*)d_in[1];
  const float* xv = (const float*)d_in[2];
  const void*  mask = d_in[3];
  const float* wq = (const float*)d_in[4];
  const float* bq = (const float*)d_in[5];
  const float* wk = (const float*)d_in[6];
  const float* bk = (const float*)d_in[7];
  const float* wv = (const float*)d_in[8];
  const float* bv = (const float*)d_in[9];
  const float* wo = (const float*)d_in[10];
  const float* bo = (const float*)d_in[11];
  float* out = (float*)d_out;

  char* ws = (char*)d_ws;
  unsigned short* Xq   = (unsigned short*)(ws);                   // 16 MiB, later Ob
  unsigned short* Ob   = (unsigned short*)(ws);                   // overlays Xq
  unsigned short* Wt   = (unsigned short*)(ws + 16777216ull);     // 8 MiB packed weights
  unsigned short* QKV  = (unsigned short*)(ws + 25165824ull);     // 48 MiB
  unsigned long long* mbits = (unsigned long long*)(ws + 75497536ull);  // 2 MiB
  // d_out overlay (32 MiB): qkv phase Xk [0,16M), Xv [16,32M); gemm_out last.
  unsigned short* Xk  = (unsigned short*)d_out;
  unsigned short* Xv  = (unsigned short*)((char*)d_out + 16777216ull);

  prep_kernel<<<32768, 256, 0, stream>>>(xq, xk, xv, Xq, Xk, Xv,
                                         wq, wk, wv, wo, Wt, mask, mbits);
  gemm_qkv_kernel<<<dim3(64, 8, 3), 256, 0, stream>>>(Xq, Xk, Xv, Wt, bq, bk, bv, QKV);
  attn_kernel<<<512, 512, 0, stream>>>(QKV, QKV + 8388608ull,
                                       QKV + 16777216ull, mbits, Ob);
  gemm_out_kernel<<<dim3(64, 8), 256, 0, stream>>>(Ob, Wt + 3ull * (HID * HID), bo, out);
}

// Round 21
// 281.966 us; speedup vs baseline: 1.0694x; 1.0222x over previous
//
#include <hip/hip_runtime.h>
#include <stdint.h>

// ---------------------------------------------------------------------------
// MHA: B=4 S=2048 H=16 Dk=Dv=64 HIDDEN=1024, fp32 in/out, bf16 MFMA compute.
// Pipeline: prep(FUSED cvt_x + pack_w + self-detecting mask_bits) ->
//           gemm_qkv(MERGED z, BK=32, z=2 writes V^T) -> attn -> gemm_out
// Round 21: s_setprio REMOVED from attn. T5 catalog: setprio pays only with
// wave role diversity (m218b); on barrier-locked lockstep structures it is
// null-to-harmful (m190: -14TF). attn evolved from 4 independent-phase waves
// (r6, when setprio was added) to an 8-wave barrier-locked block (r18) - the
// m190 regime. 4-line delete; all else byte-identical to r20 champion (288.2).
// Session ledger: 487->288.2us. attn 122.5us @87% issue; gemm_qkv at 2-phase
// template ceiling (~690TF); prep at BW floor.
// Scratch ws (74 MiB): [0,16M) Xq/Ob | [16,24M) Wt | [24,72M) QKV
//   (z=0 Q, z=1 K std; z=2 VT[bh][dv][s]) | @72M+64B bitmask (2 MiB)
// d_out overlay (32 MiB): qkv phase Xk [0,16M), Xv [16,32M); gemm_out last.
// ---------------------------------------------------------------------------

typedef __bf16 bf16x8_t __attribute__((ext_vector_type(8)));
typedef float f32x4_t __attribute__((ext_vector_type(4)));
typedef short s16x4_t __attribute__((ext_vector_type(4)));

#define HID   1024
#define SLEN  2048
#define BATCH 4
#define NH    16
#define MROWS 8192   // BATCH*SLEN
#define L2E   1.44269504f

__device__ __forceinline__ unsigned short bfbits(float f) {
  union { __bf16 h; unsigned short u; } v; v.h = (__bf16)f; return v.u;
}
__device__ __forceinline__ unsigned int packbf(float a, float b) {
  return (unsigned int)bfbits(a) | ((unsigned int)bfbits(b) << 16);
}
__device__ __forceinline__ float fast_exp2(float x) {
#if __has_builtin(__builtin_amdgcn_exp2f)
  return __builtin_amdgcn_exp2f(x);
#else
  return __exp2f(x);
#endif
}

__device__ __forceinline__ f32x4_t mfma16x16(s16x4_t a, s16x4_t b, f32x4_t c) {
#if __has_builtin(__builtin_amdgcn_mfma_f32_16x16x16bf16_1k)
  return __builtin_amdgcn_mfma_f32_16x16x16bf16_1k(a, b, c, 0, 0, 0);
#else
  asm("v_mfma_f32_16x16x16_bf16 %0, %1, %2, %0" : "+v"(c) : "v"(a), "v"(b));
  return c;
#endif
}

__device__ __forceinline__ void gload_lds16(const void* g, void* l) {
  __builtin_amdgcn_global_load_lds((const __attribute__((address_space(1))) void*)g,
                                   (__attribute__((address_space(3))) void*)l,
                                   16, 0, 0);
}

// 64-wide LDS rows (128B, 8 slots of 16B): physical slot = logical ^ (row & 7)
__device__ __forceinline__ bf16x8_t frag_ld(const unsigned short* lds, int row, int sblk) {
  int sp = sblk ^ (row & 7);
  return *(const bf16x8_t*)(lds + (row << 6) + (sp << 3));
}
// 32-wide LDS rows (64B, 4 slots of 16B): slot = logical ^ (row&3) ^ ((row>>2)&3)
__device__ __forceinline__ bf16x8_t frag_ld32(const unsigned short* lds, int row, int g) {
  int sp = g ^ (row & 3) ^ ((row >> 2) & 3);
  return *(const bf16x8_t*)(lds + (row << 5) + (sp << 3));
}

// ---- FUSED prep: cvt_x (blocks 0..24575) + pack_w (24576..28671)
//                  + mask_bits w/ in-wave dtype detect (28672..32767) ---------
__global__ __launch_bounds__(256) void prep_kernel(
    const float* __restrict__ xq, const float* __restrict__ xk,
    const float* __restrict__ xv, unsigned short* __restrict__ dq,
    unsigned short* __restrict__ dk, unsigned short* __restrict__ dv,
    const float* __restrict__ wq, const float* __restrict__ wk,
    const float* __restrict__ wv, const float* __restrict__ wo,
    unsigned short* __restrict__ wt, const void* __restrict__ maskp,
    unsigned long long* __restrict__ bits) {
  int bid = blockIdx.x;
  int tid = threadIdx.x;
  if (bid < 24576) {
    // ---- cvt_x ----
    int z = bid >> 13;
    int x = bid & 8191;
    const float* src = z == 0 ? xq : (z == 1 ? xk : xv);
    unsigned short* dst = z == 0 ? dq : (z == 1 ? dk : dv);
    size_t base = (size_t)x * 1024 + (size_t)tid * 4;
    float4 v = *(const float4*)(src + base);
    ushort4 o;
    o.x = bfbits(v.x); o.y = bfbits(v.y); o.z = bfbits(v.z); o.w = bfbits(v.w);
    *(ushort4*)(dst + base) = o;
  } else if (bid < 28672) {
    // ---- pack_w ----
    int id2 = bid - 24576;
    int z = id2 >> 10;
    int x = id2 & 1023;
    int id = x * 256 + tid;
    int n = id >> 8;
    int d0 = (id & 255) << 2;
    ushort4 o;
    if (z < 3) {
      const float* w = z == 0 ? wq : (z == 1 ? wk : wv);
      const float* base = w + (size_t)(n >> 6) * (HID * 64) + (n & 63);
      o.x = bfbits(base[(size_t)(d0 + 0) * 64]);
      o.y = bfbits(base[(size_t)(d0 + 1) * 64]);
      o.z = bfbits(base[(size_t)(d0 + 2) * 64]);
      o.w = bfbits(base[(size_t)(d0 + 3) * 64]);
    } else {
      o.x = bfbits(wo[(size_t)(d0 + 0) * HID + n]);
      o.y = bfbits(wo[(size_t)(d0 + 1) * HID + n]);
      o.z = bfbits(wo[(size_t)(d0 + 2) * HID + n]);
      o.w = bfbits(wo[(size_t)(d0 + 3) * HID + n]);
    }
    *(ushort4*)(wt + (size_t)z * (HID * HID) + (size_t)n * HID + d0) = o;
  } else {
    // ---- mask_bits with in-wave dtype detection ----
    int x = bid - 28672;
    int lane = tid & 63, wv2 = tid >> 6;
    unsigned int dvw = ((const unsigned int*)maskp)[lane];
    bool bytemask = (__ballot(dvw > 1u) != 0ull);
    size_t w0 = (size_t)x * 64 + (size_t)wv2 * 16;
    for (int it = 0; it < 16; ++it) {
      size_t word = w0 + it;
      unsigned int v;
      if (bytemask) v = ((const unsigned char*)maskp)[word * 64 + lane];
      else          v = ((const unsigned int*)maskp)[word * 64 + lane];
      unsigned long long bm = __ballot(v != 0u);
      if (lane == 0) bits[word] = bm;
    }
  }
}

// ---- MERGED QKV GEMM: 128x128 tile, BK=32, dbuf LDS 32KB --------------------
__device__ __forceinline__ void gemm_stage32(const unsigned short* __restrict__ A,
    const unsigned short* __restrict__ B, unsigned short* la, unsigned short* lb,
    int tid, int w, int kt) {
#pragma unroll
  for (int i = 0; i < 2; ++i) {
    int flat = i * 256 + tid;
    int row = flat >> 2;
    int sl = (flat & 3) ^ (row & 3) ^ ((row >> 2) & 3);  // inverse-swz SOURCE
    gload_lds16(A + (size_t)row * HID + kt + sl * 8, la + ((i * 256 + w * 64) << 3));
    gload_lds16(B + (size_t)row * HID + kt + sl * 8, lb + ((i * 256 + w * 64) << 3));
  }
}

__global__ __launch_bounds__(256) void gemm_qkv_kernel(
    const unsigned short* __restrict__ Xq, const unsigned short* __restrict__ Xk,
    const unsigned short* __restrict__ Xv, const unsigned short* __restrict__ Wt,
    const float* __restrict__ bq, const float* __restrict__ bk,
    const float* __restrict__ bv, unsigned short* __restrict__ QKV) {
  __shared__ __align__(16) unsigned short lA[2][128 * 32];
  __shared__ __align__(16) unsigned short lB[2][128 * 32];
  int z = blockIdx.z;
  const unsigned short* Ain = z == 0 ? Xq : (z == 1 ? Xk : Xv);
  const float* bias = z == 0 ? bq : (z == 1 ? bk : bv);
  float scale = z == 0 ? 0.125f * L2E : 1.0f;
  int m0 = blockIdx.x * 128, n0 = blockIdx.y * 128;
  const unsigned short* A = Ain + (size_t)m0 * HID;
  const unsigned short* B = Wt + (size_t)z * (HID * HID) + (size_t)n0 * HID;
  unsigned short* Out = QKV + (size_t)z * ((size_t)MROWS * 1024);

  f32x4_t acc[4][4] = {};
  int tid = threadIdx.x, lane = tid & 63, w = tid >> 6;
  int wr = (w >> 1) << 6, wc = (w & 1) << 6;
  int ql = lane & 15, g = lane >> 4;

  gemm_stage32(A, B, lA[0], lB[0], tid, w, 0);
  __syncthreads();
  int cur = 0;
  for (int kt = 0; kt < HID; kt += 32) {
    if (kt + 32 < HID)
      gemm_stage32(A, B, lA[cur ^ 1], lB[cur ^ 1], tid, w, kt + 32);
    const unsigned short* la = lA[cur];
    const unsigned short* lb = lB[cur];
    bf16x8_t af[4], bfr[4];
#pragma unroll
    for (int mi = 0; mi < 4; ++mi)
      af[mi] = frag_ld32(la, wr + mi * 16 + ql, g);
#pragma unroll
    for (int ni = 0; ni < 4; ++ni)
      bfr[ni] = frag_ld32(lb, wc + ni * 16 + ql, g);
#pragma unroll
    for (int mi = 0; mi < 4; ++mi)
#pragma unroll
      for (int ni = 0; ni < 4; ++ni)
        acc[mi][ni] = __builtin_amdgcn_mfma_f32_16x16x32_bf16(af[mi], bfr[ni],
                                                              acc[mi][ni], 0, 0, 0);
    __syncthreads();
    cur ^= 1;
  }

  if (z < 2) {
#pragma unroll
    for (int mi = 0; mi < 4; ++mi)
#pragma unroll
      for (int ni = 0; ni < 4; ++ni) {
        int col = n0 + wc + ni * 16 + ql;
        float bb = bias[col];
        int h = col >> 6, d = col & 63;
#pragma unroll
        for (int r = 0; r < 4; ++r) {
          int row = m0 + wr + mi * 16 + (g << 2) + r;
          int b = row >> 11, s = row & 2047;
          Out[((((size_t)b * NH + h) * SLEN + s) << 6) + d] =
              bfbits((acc[mi][ni][r] + bb) * scale);
        }
      }
  } else {
    // V: transpose in wave-private 8KB LDS, store as VT[bh][dv][s]
    unsigned short* tb = (w < 2) ? lA[w] : lB[w - 2];
    unsigned int* tu = (unsigned int*)tb;
#pragma unroll
    for (int mi = 0; mi < 4; ++mi)
#pragma unroll
      for (int ni = 0; ni < 4; ++ni) {
        int col = n0 + wc + ni * 16 + ql;
        float bb = bias[col];
        int dl = ni * 16 + ql;
        int sp0 = 8 * mi + 2 * g;
        unsigned int v0 = packbf(acc[mi][ni][0] + bb, acc[mi][ni][1] + bb);
        unsigned int v1 = packbf(acc[mi][ni][2] + bb, acc[mi][ni][3] + bb);
        int slot = (sp0 >> 2) ^ (dl & 7);
        *(uint2*)(tu + dl * 32 + slot * 4 + (sp0 & 3)) = make_uint2(v0, v1);
      }
    int srow = m0 + wr;
    int b = srow >> 11, sl_ = srow & 2047;
    int h = (n0 + wc) >> 6;
    unsigned short* VTo = Out + (((size_t)(b * NH + h) * 64) * SLEN);
#pragma unroll
    for (int pass = 0; pass < 8; ++pass) {
      int dl = (lane >> 3) + 8 * pass;
      int slot = lane & 7;
      uint4 vv = *(const uint4*)(tu + dl * 32 + ((slot ^ (dl & 7)) << 2));
      *(uint4*)(VTo + (size_t)dl * SLEN + sl_ + slot * 8) = vv;
    }
  }
}

// ---- output projection GEMM: champion BK=64 2-phase -------------------------
__device__ __forceinline__ void gemm_stage(const unsigned short* __restrict__ A,
    const unsigned short* __restrict__ B, unsigned short* la, unsigned short* lb,
    int tid, int w, int kt) {
#pragma unroll
  for (int i = 0; i < 4; ++i) {
    int flat = i * 256 + tid;
    int row = flat >> 3;
    int sl = (flat & 7) ^ (row & 7);
    gload_lds16(A + (size_t)row * HID + kt + sl * 8, la + ((i * 256 + w * 64) << 3));
    gload_lds16(B + (size_t)row * HID + kt + sl * 8, lb + ((i * 256 + w * 64) << 3));
  }
}

__global__ __launch_bounds__(256) void gemm_out_kernel(
    const unsigned short* __restrict__ Ob, const unsigned short* __restrict__ WoT,
    const float* __restrict__ bo, float* __restrict__ out) {
  __shared__ __align__(16) unsigned short lA[2][128 * 64];
  __shared__ __align__(16) unsigned short lB[2][128 * 64];
  int m0 = blockIdx.x * 128, n0 = blockIdx.y * 128;
  const unsigned short* A = Ob + (size_t)m0 * HID;
  const unsigned short* B = WoT + (size_t)n0 * HID;
  f32x4_t acc[4][4] = {};
  int tid = threadIdx.x;
  int lane = tid & 63, w = tid >> 6;
  int wr = (w >> 1) << 6, wc = (w & 1) << 6;
  gemm_stage(A, B, lA[0], lB[0], tid, w, 0);
  __syncthreads();
  int cur = 0;
  for (int kt = 0; kt < HID; kt += 64) {
    if (kt + 64 < HID)
      gemm_stage(A, B, lA[cur ^ 1], lB[cur ^ 1], tid, w, kt + 64);
    const unsigned short* la = lA[cur];
    const unsigned short* lb = lB[cur];
#pragma unroll
    for (int kk = 0; kk < 2; ++kk) {
      bf16x8_t af[4], bfr[4];
#pragma unroll
      for (int mi = 0; mi < 4; ++mi)
        af[mi] = frag_ld(la, wr + mi * 16 + (lane & 15), kk * 4 + (lane >> 4));
#pragma unroll
      for (int ni = 0; ni < 4; ++ni)
        bfr[ni] = frag_ld(lb, wc + ni * 16 + (lane & 15), kk * 4 + (lane >> 4));
#pragma unroll
      for (int mi = 0; mi < 4; ++mi)
#pragma unroll
        for (int ni = 0; ni < 4; ++ni)
          acc[mi][ni] = __builtin_amdgcn_mfma_f32_16x16x32_bf16(af[mi], bfr[ni],
                                                                acc[mi][ni], 0, 0, 0);
    }
    __syncthreads();
    cur ^= 1;
  }
#pragma unroll
  for (int mi = 0; mi < 4; ++mi)
#pragma unroll
    for (int ni = 0; ni < 4; ++ni) {
      int col = n0 + wc + ni * 16 + (lane & 15);
      float bb = bo[col];
#pragma unroll
      for (int r = 0; r < 4; ++r) {
        int row = m0 + wr + mi * 16 + ((lane >> 4) << 2) + r;
        out[(size_t)row * HID + col] = acc[mi][ni][r] + bb;
      }
    }
}

// ---- flash attention: swapped QK^T, static-max softmax, register-P PV -------
// QBLK=256 (8 waves), KVBLK=128 (two 64-kv halves per barrier). No setprio.
__global__ __launch_bounds__(512) void attn_kernel(
    const unsigned short* __restrict__ Q, const unsigned short* __restrict__ K,
    const unsigned short* __restrict__ VT, const unsigned long long* __restrict__ mbits,
    unsigned short* __restrict__ O) {
  __shared__ __align__(16) unsigned short lK[2][2][64 * 64];  // [buf][half][kv][d]
  __shared__ __align__(16) unsigned short lV[2][2][64 * 64];  // [buf][half][dv][kv]
  int tid = threadIdx.x, lane = tid & 63, w = tid >> 6;       // w in 0..7
  int g = lane >> 4, ql = lane & 15;
  int bid = blockIdx.x;                         // 512 blocks = 8 qt x 64 bh
  int bh = (bid & 7) * 8 + ((bid >> 3) >> 3);   // XCD-grouped, bijective
  int qt = (bid >> 3) & 7;
  int b = bh >> 4, h = bh & 15;
  int q0 = qt * 256;
  const unsigned short* Qb = Q + (size_t)bh * (SLEN * 64);

  // staging: 512 threads, 1 gload per K-half and V-half each (8KB per half)
  int r0 = tid >> 3;
  int s0 = (tid & 7) ^ (r0 & 7);
  const unsigned short* kS0 = K + (size_t)bh * (SLEN * 64) + (size_t)r0 * 64 + s0 * 8;
  const unsigned short* vS0 = VT + (size_t)bh * (64 * SLEN) + (size_t)r0 * SLEN + s0 * 8;
  int doff = tid << 3;
  const unsigned long long* mp0 = mbits + ((size_t)b * SLEN + (q0 + w * 32 + ql)) * 32;
  const unsigned long long* mp1 = mp0 + 16 * 32;

  int vbyte0 = (ql << 7) + (((g >> 1) ^ (ql & 7)) << 4) + ((g & 1) << 3);

  bf16x8_t qf[2][2];
#pragma unroll
  for (int mi = 0; mi < 2; ++mi)
#pragma unroll
    for (int kk = 0; kk < 2; ++kk) {
      int row = q0 + w * 32 + mi * 16 + ql;
      qf[mi][kk] = *(const bf16x8_t*)(Qb + (size_t)row * 64 + kk * 32 + g * 8);
    }

  s16x4_t ones4 = {0x3F80, 0x3F80, 0x3F80, 0x3F80};  // 4x bf16 1.0

  f32x4_t aco[2][4] = {};     // O^T: dv=dvf*16+4g+r, q=mi*16+ql
  f32x4_t slacc[2] = {};      // l[q=ql] via ones-MFMA

#pragma unroll
  for (int hh = 0; hh < 2; ++hh) {
    gload_lds16(kS0 + hh * 4096, (unsigned short*)lK[0][hh] + doff);
    gload_lds16(vS0 + hh * 64,   (unsigned short*)lV[0][hh] + doff);
  }
  kS0 += 8192; vS0 += 128;
  __syncthreads();

  int cur = 0;
  for (int kt = 0; kt < SLEN / 128; ++kt) {
    if (kt + 1 < SLEN / 128) {
#pragma unroll
      for (int hh = 0; hh < 2; ++hh) {
        gload_lds16(kS0 + hh * 4096, (unsigned short*)lK[cur ^ 1][hh] + doff);
        gload_lds16(vS0 + hh * 64,   (unsigned short*)lV[cur ^ 1][hh] + doff);
      }
      kS0 += 8192; vS0 += 128;
    }

#pragma unroll
    for (int hh = 0; hh < 2; ++hh) {
      unsigned long long bg0 = mp0[2 * kt + hh] >> (4 * g);
      unsigned long long bg1 = mp1[2 * kt + hh] >> (4 * g);

      const unsigned short* kbuf = lK[cur][hh];
      const unsigned short* vbuf = lV[cur][hh];

      f32x4_t st[2][4];
#pragma unroll
      for (int mi = 0; mi < 2; ++mi)
#pragma unroll
        for (int ni = 0; ni < 4; ++ni) st[mi][ni] = (f32x4_t){0.f, 0.f, 0.f, 0.f};
#pragma unroll
      for (int kk = 0; kk < 2; ++kk) {
        bf16x8_t kf[4];
#pragma unroll
        for (int ni = 0; ni < 4; ++ni)
          kf[ni] = frag_ld(kbuf, ni * 16 + ql, kk * 4 + g);
#pragma unroll
        for (int mi = 0; mi < 2; ++mi)
#pragma unroll
          for (int ni = 0; ni < 4; ++ni)
            st[mi][ni] = __builtin_amdgcn_mfma_f32_16x16x32_bf16(kf[ni], qf[mi][kk],
                                                                 st[mi][ni], 0, 0, 0);
      }

      unsigned int pb[2][4][2];
#pragma unroll
      for (int mi = 0; mi < 2; ++mi) {
        unsigned long long bgs = mi ? bg1 : bg0;
        unsigned int mw0 = (unsigned int)bgs;
        unsigned int mw1 = (unsigned int)(bgs >> 32);
#pragma unroll
        for (int ni = 0; ni < 4; ++ni) {
          unsigned int mword = (ni < 2) ? mw0 : mw1;
          int base = (ni & 1) * 16;
          float p[4];
#pragma unroll
          for (int r = 0; r < 4; ++r) {
            float e = fast_exp2(st[mi][ni][r]);
            p[r] = ((mword >> (base + r)) & 1u) ? e : 0.f;
          }
          pb[mi][ni][0] = packbf(p[0], p[1]);
          pb[mi][ni][1] = packbf(p[2], p[3]);
        }
      }

#pragma unroll
      for (int c = 0; c < 4; ++c) {
        s16x4_t vfa[4];
#pragma unroll
        for (int dvf = 0; dvf < 4; ++dvf) {
          union { uint2 u; s16x4_t s; } t;
          t.u = *(const uint2*)((const char*)vbuf + ((vbyte0 ^ (c << 5)) + dvf * 2048));
          vfa[dvf] = t.s;
        }
#pragma unroll
        for (int mi = 0; mi < 2; ++mi) {
          union { unsigned int u[2]; s16x4_t s; } pp;
          pp.u[0] = pb[mi][c][0]; pp.u[1] = pb[mi][c][1];
          slacc[mi] = mfma16x16(ones4, pp.s, slacc[mi]);
#pragma unroll
          for (int dvf = 0; dvf < 4; ++dvf)
            aco[mi][dvf] = mfma16x16(vfa[dvf], pp.s, aco[mi][dvf]);
        }
      }
    }

    __syncthreads();
    cur ^= 1;
  }

  // epilogue: normalize O^T, transpose through lK scratch (wave-private rows)
  unsigned short* eb = (unsigned short*)lK;  // 256 rows x 128B = 32KB = lK
#pragma unroll
  for (int mi = 0; mi < 2; ++mi) {
    float inv = 1.0f / slacc[mi][0];
    int prow = w * 32 + mi * 16 + ql;        // 0..255
#pragma unroll
    for (int dvf = 0; dvf < 4; ++dvf) {
      unsigned int lo = packbf(aco[mi][dvf][0] * inv, aco[mi][dvf][1] * inv);
      unsigned int hi = packbf(aco[mi][dvf][2] * inv, aco[mi][dvf][3] * inv);
      int sl = (2 * dvf + (g >> 1)) ^ (prow & 7);
      *(uint2*)((char*)eb + prow * 128 + sl * 16 + (g & 1) * 8) = make_uint2(lo, hi);
    }
  }
#pragma unroll
  for (int it = 0; it < 8; ++it) {
    int rloc = g + 4 * it;
    int row = w * 32 + rloc;
    int sl = (ql >> 1) ^ (row & 7);
    uint2 v = *(const uint2*)((const char*)eb + row * 128 + sl * 16 + (ql & 1) * 8);
    int qrow = q0 + row;
    *(uint2*)(O + (((size_t)b * SLEN + qrow) << 10) + h * 64 + ql * 4) = v;
  }
}

// ---------------------------------------------------------------------------
extern "C" void kernel_launch(void* const* d_in, const int* in_sizes, int n_in,
                              void* d_out, int out_size, void* d_ws, size_t ws_size,
                              hipStream_t stream) {
  (void)in_sizes; (void)n_in; (void)out_size; (void)ws_size;
  const float* xq = (const float*)d_in[0];
  const float* xk = (const float*)d_in[1];
  const float* xv = (const float*)d_in[2];
  const void*  mask = d_in[3];
  const float* wq = (const float*)d_in[4];
  const float* bq = (const float*)d_in[5];
  const float* wk = (const float*)d_in[6];
  const float* bk = (const float*)d_in[7];
  const float* wv = (const float*)d_in[8];
  const float* bv = (const float*)d_in[9];
  const float* wo = (const float*)d_in[10];
  const float* bo = (const float*)d_in[11];
  float* out = (float*)d_out;

  char* ws = (char*)d_ws;
  unsigned short* Xq   = (unsigned short*)(ws);                   // 16 MiB, later Ob
  unsigned short* Ob   = (unsigned short*)(ws);                   // overlays Xq
  unsigned short* Wt   = (unsigned short*)(ws + 16777216ull);     // 8 MiB packed weights
  unsigned short* QKV  = (unsigned short*)(ws + 25165824ull);     // 48 MiB
  unsigned long long* mbits = (unsigned long long*)(ws + 75497536ull);  // 2 MiB
  // d_out overlay (32 MiB): qkv phase Xk [0,16M), Xv [16,32M); gemm_out last.
  unsigned short* Xk  = (unsigned short*)d_out;
  unsigned short* Xv  = (unsigned short*)((char*)d_out + 16777216ull);

  prep_kernel<<<32768, 256, 0, stream>>>(xq, xk, xv, Xq, Xk, Xv,
                                         wq, wk, wv, wo, Wt, mask, mbits);
  gemm_qkv_kernel<<<dim3(64, 8, 3), 256, 0, stream>>>(Xq, Xk, Xv, Wt, bq, bk, bv, QKV);
  attn_kernel<<<512, 512, 0, stream>>>(QKV, QKV + 8388608ull,
                                       QKV + 16777216ull, mbits, Ob);
  gemm_out_kernel<<<dim3(64, 8), 256, 0, stream>>>(Ob, Wt + 3ull * (HID * HID), bo, out);
}